// Round 2
// baseline (12473.782 us; speedup 1.0000x reference)
//
#include <hip/hip_runtime.h>
#include <hip/hip_bf16.h>

#define HH 512
#define VV 50257
#define TL 512
#define NT 256
#define DYN_LDS 98304   // ~4 KB used; large request forces 1 block/CU (co-residency for 256 blocks)

typedef __attribute__((ext_vector_type(8))) short short8;
typedef __attribute__((ext_vector_type(4))) float floatx4;

__device__ __forceinline__ unsigned short f2bf(float f) {
  union { float f; unsigned int u; } v; v.f = f;
  unsigned int r = (v.u + 0x7fffu + ((v.u >> 16) & 1u)) >> 16;
  return (unsigned short)r;
}
__device__ __forceinline__ float bf2f(unsigned short h) {
  union { unsigned int u; float f; } v; v.u = ((unsigned int)h) << 16;
  return v.f;
}

// ---- P1: column max of alpha_exp (+eps) ----
__global__ void colmaxK(const float* __restrict__ A, float* __restrict__ cmax) {
  __shared__ float red[4][64];
  int x = threadIdx.x & 63;
  int y = threadIdx.x >> 6;
  int c = blockIdx.x * 64 + x;
  float m = -INFINITY;
  for (int j = y; j < HH; j += 4) m = fmaxf(m, A[j * HH + c]);
  red[y][x] = m;
  __syncthreads();
  if (y == 0)
    cmax[c] = fmaxf(fmaxf(red[0][x], red[1][x]), fmaxf(red[2][x], red[3][x])) + 1e-12f;
}

// ---- P2: bf16 Wn pre-swizzled into MFMA B-fragment order ----
__global__ void buildWfK(const float* __restrict__ A, const float* __restrict__ cmax,
                         uint4* __restrict__ Wf) {
  int gid = blockIdx.x * 256 + threadIdx.x;  // 0..32767
  int T = gid >> 10;
  int k = (gid >> 6) & 15;
  int L = gid & 63;
  int n = T * 16 + (L & 15);
  int k0 = 32 * k + (L >> 4) * 8;
  float inv = 1.0f / cmax[n];
  alignas(16) unsigned short o[8];
#pragma unroll
  for (int j = 0; j < 8; ++j)
    o[j] = f2bf((A[(k0 + j) * HH + n] + 1e-12f) * inv);
  Wf[gid] = *(const uint4*)o;
}

// ---- P3: Ptab[v][n] = bf16( exp(beta[n][v]) * cmax[n] ) ----
__global__ void buildPtab(const float* __restrict__ beta, const float* __restrict__ cmax,
                          unsigned short* __restrict__ Ptab) {
  __shared__ float tile[32][33];
  int v0 = blockIdx.x * 32, h0 = blockIdx.y * 32;
  int tx = threadIdx.x, ty = threadIdx.y;
#pragma unroll
  for (int k = 0; k < 4; ++k) {
    int v = v0 + tx;
    if (v < VV) tile[ty + 8 * k][tx] = beta[(h0 + ty + 8 * k) * VV + v];
  }
  __syncthreads();
  float cm = cmax[h0 + tx];
#pragma unroll
  for (int k = 0; k < 4; ++k) {
    int v = v0 + ty + 8 * k;
    if (v < VV) Ptab[(long)v * HH + h0 + tx] = f2bf(__expf(tile[tx][ty + 8 * k]) * cm);
  }
}

// ---- Main: 256 blocks = 64 batches x 4 n-parts; W slice (128x512) fully in registers.
// Rescale scheme = the verified 1-step-stale CURRENT-scale max (s_t = a_{t-1}, zero-memory,
// perfectly conditioned): per-wave maxes of u_{t-1} ride with y_{t-1} under the same flag.
//   flags[b][p*4+w] = #steps wave published (flag >= t  <=>  y_{t-1}, M-parts_{t-1} visible)
//   ybuf depth 2 (y_s in slot s&1); mbuf depth 4 (per-wave maxes of u_s in slot s&3).
//   Overwrite of ybuf slot s&1 at step s+2 is gated by flag >= s+2 => consumers finished
//   their step-(s+1) gather of y_s. Same argument for mbuf at depth 4.
__global__ __launch_bounds__(NT) __attribute__((amdgpu_waves_per_eu(1, 1)))
void hmm_main(const uint4* __restrict__ Wf,
              const unsigned short* __restrict__ Ptab,
              const float* __restrict__ gamma,
              const float* __restrict__ cmax,
              const int* __restrict__ ids,
              float* __restrict__ out,
              unsigned* __restrict__ flags,   // [64][16] per-wave step counters
              float* __restrict__ mbuf,       // [4][64][16] per-wave maxes
              unsigned* __restrict__ ybuf) {  // [2][64][256] dwords (2 bf16 each)
  extern __shared__ char dls[];
  unsigned* xls = (unsigned*)dls;            // [2][256] staged y dwords (double-buffered)
  int* ids_l = (int*)(dls + 2048);           // [512]

  const int bid = blockIdx.x;
  const int b = bid & 63, p = bid >> 6;      // parts of batch b: blocks b+64p
  const int tid = threadIdx.x;
  const int w = tid >> 6, L = tid & 63;
  const int l16 = L & 15, q = L >> 4, half = (L >> 5) & 1;
  const long bT = (long)b * TL;

  unsigned* fbase = flags + b * 16;
  const int myf = b * 16 + p * 4 + w;

  ids_l[tid] = ids[bT + tid];
  ids_l[tid + 256] = ids[bT + tid + 256];

  // W fragments: wave w owns global n-tiles 8p+2w, 8p+2w+1 (register-resident, 128 VGPR)
  short8 w0[16], w1[16];
  const int T0 = 8 * p + 2 * w;
#pragma unroll
  for (int k = 0; k < 16; ++k) {
    w0[k] = __builtin_bit_cast(short8, Wf[(T0 * 16 + k) * 64 + L]);
    w1[k] = __builtin_bit_cast(short8, Wf[((T0 + 1) * 16 + k) * 64 + L]);
  }

  // lane's output row (values replicated across L^16; q does not affect n)
  const int n = 128 * p + 32 * w + half * 16 + l16;
  const int ydw = 64 * p + 16 * w + half * 8 + (l16 >> 1);
  const bool ystorer = ((L & 1) == 0) && ((L & 16) == 0);

  float A = 0.f;

  // ---- t = 0: publish y_0 = u_0 raw (C_1 = 1, A = 0) and per-wave maxes of u_0 ----
  {
    const int id0 = ids[bT];
    float u0 = gamma[n] * bf2f(Ptab[(long)id0 * HH + n]) / cmax[n];
    float m = u0;  // wave max over 32 distinct values (skip mask 16: replicated)
    m = fmaxf(m, __shfl_xor(m, 1));
    m = fmaxf(m, __shfl_xor(m, 2));
    m = fmaxf(m, __shfl_xor(m, 4));
    m = fmaxf(m, __shfl_xor(m, 8));
    m = fmaxf(m, __shfl_xor(m, 32));
    unsigned short yv = f2bf(u0);
    unsigned ov = __shfl_xor((unsigned)yv, 1);
    if (ystorer)
      __hip_atomic_store(&ybuf[b * 256 + ydw], (unsigned)yv | (ov << 16),
                         __ATOMIC_RELAXED, __HIP_MEMORY_SCOPE_AGENT);
    if (L == 0)
      __hip_atomic_store(&mbuf[b * 16 + p * 4 + w], m, __ATOMIC_RELAXED,
                         __HIP_MEMORY_SCOPE_AGENT);
    __syncthreads();  // ids_l visible block-wide for all later iterations
    if (L == 0)  // release orders this wave's ybuf/mbuf stores (vmcnt drain)
      __hip_atomic_fetch_add(&flags[myf], 1u, __ATOMIC_RELEASE, __HIP_MEMORY_SCOPE_AGENT);
  }

  for (int t = 1; t < TL; ++t) {
    const int idt = ids_l[t];
    const unsigned short pvv = Ptab[(long)idt * HH + n];  // prefetch, used at epilogue

    // poll: all 16 producer waves of batch b published step t-1
    bool done;
    do {
      unsigned f = 0xffffffffu;
      if (L < 16) f = __hip_atomic_load(&fbase[L], __ATOMIC_ACQUIRE, __HIP_MEMORY_SCOPE_AGENT);
      done = __all((L < 16) ? (f >= (unsigned)t) : 1);
      if (!done) __builtin_amdgcn_s_sleep(1);
    } while (!done);

    // gather y_{t-1}: 1 coherent dword/thread (256 dwords = full 512-vector, linear layout)
    const unsigned dw = __hip_atomic_load(&ybuf[((t - 1) & 1) * 16384 + b * 256 + tid],
                                          __ATOMIC_RELAXED, __HIP_MEMORY_SCOPE_AGENT);

    // G = global max of u_{t-1} (current scale): reduce 16 per-wave maxes
    float mv = -1e30f;
    if (L < 16)
      mv = __hip_atomic_load(&mbuf[((t - 1) & 3) * 1024 + b * 16 + L],
                             __ATOMIC_RELAXED, __HIP_MEMORY_SCOPE_AGENT);
    mv = fmaxf(mv, __shfl_xor(mv, 1));
    mv = fmaxf(mv, __shfl_xor(mv, 2));
    mv = fmaxf(mv, __shfl_xor(mv, 4));
    mv = fmaxf(mv, __shfl_xor(mv, 8));
    const float G = fmaxf(__shfl(mv, 0), 1e-30f);
    const float rG = 1.0f / G;

    const int sl = (t - 1) & 1;
    xls[sl * 256 + tid] = dw;
    __syncthreads();  // sole barrier/iter; xls dbuf makes cross-iter overwrite safe

    // z = Wn y : 32 MFMA/wave, 4 independent 8-deep chains
    const unsigned short* xs = (const unsigned short*)(xls + sl * 256);
    floatx4 a0l = {0.f, 0.f, 0.f, 0.f}, a0h = {0.f, 0.f, 0.f, 0.f};
    floatx4 a1l = {0.f, 0.f, 0.f, 0.f}, a1h = {0.f, 0.f, 0.f, 0.f};
#pragma unroll
    for (int k = 0; k < 8; ++k) {
      short8 af = *(const short8*)(xs + k * 32 + q * 8);  // quad-broadcast A rows
      a0l = __builtin_amdgcn_mfma_f32_16x16x32_bf16(af, w0[k], a0l, 0, 0, 0);
      a1l = __builtin_amdgcn_mfma_f32_16x16x32_bf16(af, w1[k], a1l, 0, 0, 0);
    }
#pragma unroll
    for (int k = 8; k < 16; ++k) {
      short8 af = *(const short8*)(xs + k * 32 + q * 8);
      a0h = __builtin_amdgcn_mfma_f32_16x16x32_bf16(af, w0[k], a0h, 0, 0, 0);
      a1h = __builtin_amdgcn_mfma_f32_16x16x32_bf16(af, w1[k], a1h, 0, 0, 0);
    }
    const float z = half ? (a1l[0] + a1h[0]) : (a0l[0] + a0h[0]);
    const float un = z * bf2f(pvv);

    if (t == TL - 1) {
      if ((L & 16) == 0) out[(long)b * HH + n] = __logf(fmaxf(un, 1e-37f)) + A;
    } else {
      A += __logf(G);  // C_{t+1} = C_t * G_t  (y_t divided by G below)
      float m = un;    // per-wave max of CURRENT-scale u_t, rides with y_t
      m = fmaxf(m, __shfl_xor(m, 1));
      m = fmaxf(m, __shfl_xor(m, 2));
      m = fmaxf(m, __shfl_xor(m, 4));
      m = fmaxf(m, __shfl_xor(m, 8));
      m = fmaxf(m, __shfl_xor(m, 32));
      unsigned short yv = f2bf(un * rG);
      unsigned ov = __shfl_xor((unsigned)yv, 1);
      if (ystorer)
        __hip_atomic_store(&ybuf[(t & 1) * 16384 + b * 256 + ydw], (unsigned)yv | (ov << 16),
                           __ATOMIC_RELAXED, __HIP_MEMORY_SCOPE_AGENT);
      if (L == 0)
        __hip_atomic_store(&mbuf[(t & 3) * 1024 + b * 16 + p * 4 + w], m,
                           __ATOMIC_RELAXED, __HIP_MEMORY_SCOPE_AGENT);
      if (L == 0)  // release drains this wave's vmcnt -> y/m stores visible first
        __hip_atomic_fetch_add(&flags[myf], 1u, __ATOMIC_RELEASE, __HIP_MEMORY_SCOPE_AGENT);
    }
  }
}

extern "C" void kernel_launch(void* const* d_in, const int* in_sizes, int n_in,
                              void* d_out, int out_size, void* d_ws, size_t ws_size,
                              hipStream_t stream) {
  const float* alpha_exp = (const float*)d_in[0];
  const float* beta = (const float*)d_in[1];
  const float* gamma = (const float*)d_in[2];
  const int* ids = (const int*)d_in[3];
  float* out = (float*)d_out;

  char* ws = (char*)d_ws;
  float* cmax = (float*)(ws + 0);                         // [0, 2048)
  uint4* Wf = (uint4*)(ws + 4096);                        // [4096, 528384)
  unsigned short* Ptab = (unsigned short*)(ws + 528384);  // ~51.5 MB
  unsigned* flags = (unsigned*)(ws + (64u << 20));        // 4 KB, zeroed each launch
  float* mbuf = (float*)(ws + (64u << 20) + 4096);        // 16 KB
  unsigned* ybuf = (unsigned*)(ws + (64u << 20) + 20480); // 128 KB (ws proven >= 104 MB)

  // idempotent, host-side (not a stream op; graph-capture safe), every call:
  (void)hipFuncSetAttribute((const void*)hmm_main,
                            hipFuncAttributeMaxDynamicSharedMemorySize, DYN_LDS);

  (void)hipMemsetAsync(flags, 0, 4096, stream);  // reset step counters per launch/replay

  colmaxK<<<8, 256, 0, stream>>>(alpha_exp, cmax);
  buildWfK<<<128, 256, 0, stream>>>(alpha_exp, cmax, Wf);
  dim3 gT((VV + 31) / 32, HH / 32), bTd(32, 8);
  buildPtab<<<gT, bTd, 0, stream>>>(beta, cmax, Ptab);

  hmm_main<<<256, NT, DYN_LDS, stream>>>(Wf, Ptab, gamma, cmax, ids, out, flags, mbuf, ybuf);
}

// Round 3
// 1128.298 us; speedup vs baseline: 11.0554x; 11.0554x over previous
//
#include <hip/hip_runtime.h>
#include <hip/hip_bf16.h>

#define HH 512
#define VV 50257
#define TL 512
#define NT 256
#define DYN_LDS 135168  // 128KB W-tiles + 2KB xbuf + 2KB ids

typedef __attribute__((ext_vector_type(8))) short short8;
typedef __attribute__((ext_vector_type(4))) float floatx4;

__device__ __forceinline__ unsigned short f2bf(float f) {
  union { float f; unsigned int u; } v; v.f = f;
  unsigned int r = (v.u + 0x7fffu + ((v.u >> 16) & 1u)) >> 16;
  return (unsigned short)r;
}
__device__ __forceinline__ float bf2f(unsigned short h) {
  union { unsigned int u; float f; } v; v.u = ((unsigned int)h) << 16;
  return v.f;
}

// ---- P1: column max of alpha_exp (+eps) ----
__global__ void colmaxK(const float* __restrict__ A, float* __restrict__ cmax) {
  __shared__ float red[4][64];
  int x = threadIdx.x & 63;
  int y = threadIdx.x >> 6;
  int c = blockIdx.x * 64 + x;
  float m = -INFINITY;
  for (int j = y; j < HH; j += 4) m = fmaxf(m, A[j * HH + c]);
  red[y][x] = m;
  __syncthreads();
  if (y == 0)
    cmax[c] = fmaxf(fmaxf(red[0][x], red[1][x]), fmaxf(red[2][x], red[3][x])) + 1e-12f;
}

// ---- P2: bf16 Wn pre-swizzled into MFMA B-fragment order ----
__global__ void buildWfK(const float* __restrict__ A, const float* __restrict__ cmax,
                         uint4* __restrict__ Wf) {
  int gid = blockIdx.x * 256 + threadIdx.x;  // 0..32767
  int T = gid >> 10;
  int k = (gid >> 6) & 15;
  int L = gid & 63;
  int n = T * 16 + (L & 15);
  int k0 = 32 * k + (L >> 4) * 8;
  float inv = 1.0f / cmax[n];
  alignas(16) unsigned short o[8];
#pragma unroll
  for (int j = 0; j < 8; ++j)
    o[j] = f2bf((A[(k0 + j) * HH + n] + 1e-12f) * inv);
  Wf[gid] = *(const uint4*)o;
}

// ---- P3: Ptab[v][n] = bf16( exp(beta[n][v]) * cmax[n] ) ----
__global__ void buildPtab(const float* __restrict__ beta, const float* __restrict__ cmax,
                          unsigned short* __restrict__ Ptab) {
  __shared__ float tile[32][33];
  int v0 = blockIdx.x * 32, h0 = blockIdx.y * 32;
  int tx = threadIdx.x, ty = threadIdx.y;
#pragma unroll
  for (int k = 0; k < 4; ++k) {
    int v = v0 + tx;
    if (v < VV) tile[ty + 8 * k][tx] = beta[(h0 + ty + 8 * k) * VV + v];
  }
  __syncthreads();
  float cm = cmax[h0 + tx];
#pragma unroll
  for (int k = 0; k < 4; ++k) {
    int v = v0 + ty + 8 * k;
    if (v < VV) Ptab[(long)v * HH + h0 + tx] = f2bf(__expf(tile[tx][ty + 8 * k]) * cm);
  }
}

// ---- Main: 64 blocks (one batch each), 4 waves, 1 wave/SIMD.
// W split that actually fits the 512-reg/wave unified file:
//   7 k-tiles AGPR (224a) + acc (32a) = 256a ; 5 k-tiles VGPR (160v) ; 4 k-tiles LDS (128KB).
// LDS k-tile reads issued one group ahead (latency hidden under reg-tile MFMAs).
// G_t = max(stored y_{t-1}) via u16 max (bf16>=0) — redundant per-wave, overlapped with
// MFMA, no cross-wave reduce on the critical path. Zero-memory scale recurrence:
// D_t = D_{t-1}*G_t, log D_{t+1} = log max alpha_t (same conditioning as verified scheme).
__global__ __launch_bounds__(NT) __attribute__((amdgpu_waves_per_eu(1, 1)))
void hmm_main(const uint4* __restrict__ Wf,
              const unsigned short* __restrict__ Ptab,
              const float* __restrict__ gamma,
              const float* __restrict__ cmax,
              const int* __restrict__ ids,
              float* __restrict__ out) {
  extern __shared__ char dls[];
  uint4* wlds = (uint4*)dls;                               // [0,131072): W k-tiles 12..15
  unsigned short* xbuf = (unsigned short*)(dls + 131072);  // [2][512] bf16
  int* ids_l = (int*)(dls + 133120);                       // [512]

  const int b = blockIdx.x, tid = threadIdx.x;
  const int w = tid >> 6, L = tid & 63;
  const int l16 = L & 15, q = L >> 4;
  const long bT = (long)b * TL;

  ids_l[tid] = ids[bT + tid];
  ids_l[tid + 256] = ids[bT + tid + 256];

  // stage LDS-resident W k-tiles 12..15 (layout == read order: base + lane*16)
#pragma unroll
  for (int i = 0; i < 32; ++i) {
    int e = tid + i * 256;            // 0..8191
    int Le = e & 63, r = e >> 6;
    int T = r & 31, kk = r >> 5;
    wlds[e] = Wf[(T * 16 + 12 + kk) * 64 + Le];
  }

  // register-resident W: wave w owns n-tiles 8w..8w+7
  short8 wa[8][7];  // k = 0..6  -> AGPR
  short8 wv[8][5];  // k = 7..11 -> VGPR
#pragma unroll
  for (int tau = 0; tau < 8; ++tau) {
#pragma unroll
    for (int k = 0; k < 7; ++k)
      wa[tau][k] = __builtin_bit_cast(short8, Wf[((8 * w + tau) * 16 + k) * 64 + L]);
#pragma unroll
    for (int k = 0; k < 5; ++k)
      wv[tau][k] = __builtin_bit_cast(short8, Wf[((8 * w + tau) * 16 + 7 + k) * 64 + L]);
  }

  // this lane's two output columns: tiles 2q, 2q+1 at col l16
  const int n0 = 128 * w + 32 * q + l16;
  const int n1 = n0 + 16;

  float A = 0.f;

  // ---- t = 0: store y_0 = u_0 raw (D_0 = 1, A = 0) ----
  {
    const int id0 = ids[bT];
    float u0 = gamma[n0] * bf2f(Ptab[(long)id0 * HH + n0]) / cmax[n0];
    float u1 = gamma[n1] * bf2f(Ptab[(long)id0 * HH + n1]) / cmax[n1];
    xbuf[n0] = f2bf(u0);
    xbuf[n1] = f2bf(u1);
    __syncthreads();
  }

  // Ptab prefetch pipeline: pv for step t loaded during step t-1
  int id1 = ids_l[1];
  unsigned short pv0c = Ptab[(long)id1 * HH + n0];
  unsigned short pv1c = Ptab[(long)id1 * HH + n1];

  for (int t = 1; t < TL; ++t) {
    const int pr = (t - 1) & 1, pw = t & 1;
    const int idn = ids_l[(t + 1 < TL) ? (t + 1) : t];
    const unsigned short pv0n = Ptab[(long)idn * HH + n0];  // for t+1
    const unsigned short pv1n = Ptab[(long)idn * HH + n1];

    const unsigned short* xb = xbuf + pr * 512;

    // G = max y_{t-1}: one b128 row-read + in-lane u16 max + 6 shfl (overlaps MFMA)
    short8 g8 = *(const short8*)(xb + 8 * L);
    unsigned gm = (unsigned)(unsigned short)g8[0];
#pragma unroll
    for (int j = 1; j < 8; ++j) {
      unsigned x = (unsigned)(unsigned short)g8[j];
      gm = gm > x ? gm : x;
    }
#pragma unroll
    for (int msk = 1; msk <= 32; msk <<= 1) {
      unsigned o = __shfl_xor(gm, msk);
      gm = gm > o ? gm : o;
    }
    const float G = fmaxf(bf2f((unsigned short)gm), 1e-30f);

    floatx4 acc[8];
#pragma unroll
    for (int tau = 0; tau < 8; ++tau) acc[tau] = (floatx4){0.f, 0.f, 0.f, 0.f};

    const uint4* wp = wlds + (8 * w) * 64 + L;
#pragma unroll
    for (int g = 0; g < 4; ++g) {
      // issue LDS k-tile (12+g) reads now; consumed after 3 reg-tiles (~190cy cover)
      short8 wl[8];
#pragma unroll
      for (int tau = 0; tau < 8; ++tau)
        wl[tau] = __builtin_bit_cast(short8, wp[(g * 32 + tau) * 64]);
#pragma unroll
      for (int j = 0; j < 3; ++j) {
        const int k = 3 * g + j;  // 0..11, static after unroll
        short8 af = *(const short8*)(xb + k * 32 + q * 8);  // quad-broadcast A rows
        if (k < 7) {
#pragma unroll
          for (int tau = 0; tau < 8; ++tau)
            asm("v_mfma_f32_16x16x32_bf16 %0, %1, %2, %0"
                : "+a"(acc[tau]) : "v"(af), "a"(wa[tau][k]));
        } else {
#pragma unroll
          for (int tau = 0; tau < 8; ++tau)
            asm("v_mfma_f32_16x16x32_bf16 %0, %1, %2, %0"
                : "+a"(acc[tau]) : "v"(af), "v"(wv[tau][k - 7]));
        }
      }
      short8 afl = *(const short8*)(xb + (12 + g) * 32 + q * 8);
#pragma unroll
      for (int tau = 0; tau < 8; ++tau)
        acc[tau] = __builtin_amdgcn_mfma_f32_16x16x32_bf16(afl, wl[tau], acc[tau], 0, 0, 0);
    }

    float z0 = (q < 2) ? (q == 0 ? acc[0][0] : acc[2][0])
                       : (q == 2 ? acc[4][0] : acc[6][0]);
    float z1 = (q < 2) ? (q == 0 ? acc[1][0] : acc[3][0])
                       : (q == 2 ? acc[5][0] : acc[7][0]);
    float un0 = z0 * bf2f(pv0c);
    float un1 = z1 * bf2f(pv1c);

    if (t == TL - 1) {
      out[(long)b * HH + n0] = __logf(fmaxf(un0, 1e-37f)) + A;
      out[(long)b * HH + n1] = __logf(fmaxf(un1, 1e-37f)) + A;
    } else {
      A += __logf(G);
      const float rG = 1.0f / G;
      xbuf[pw * 512 + n0] = f2bf(un0 * rG);
      xbuf[pw * 512 + n1] = f2bf(un1 * rG);
    }
    pv0c = pv0n;
    pv1c = pv1n;
    __syncthreads();
  }
}

extern "C" void kernel_launch(void* const* d_in, const int* in_sizes, int n_in,
                              void* d_out, int out_size, void* d_ws, size_t ws_size,
                              hipStream_t stream) {
  const float* alpha_exp = (const float*)d_in[0];
  const float* beta = (const float*)d_in[1];
  const float* gamma = (const float*)d_in[2];
  const int* ids = (const int*)d_in[3];
  float* out = (float*)d_out;

  char* ws = (char*)d_ws;
  float* cmax = (float*)(ws + 0);                         // [0, 2048)
  uint4* Wf = (uint4*)(ws + 4096);                        // [4096, 528384)
  unsigned short* Ptab = (unsigned short*)(ws + 528384);  // ~51.5 MB (ws proven >= 104 MB)

  // idempotent, host-side (not a stream op; graph-capture safe), every call:
  (void)hipFuncSetAttribute((const void*)hmm_main,
                            hipFuncAttributeMaxDynamicSharedMemorySize, DYN_LDS);

  colmaxK<<<8, 256, 0, stream>>>(alpha_exp, cmax);
  buildWfK<<<128, 256, 0, stream>>>(alpha_exp, cmax, Wf);
  dim3 gT((VV + 31) / 32, HH / 32), bTd(32, 8);
  buildPtab<<<gT, bTd, 0, stream>>>(beta, cmax, Ptab);

  hmm_main<<<64, NT, DYN_LDS, stream>>>(Wf, Ptab, gamma, cmax, ids, out);
}

// Round 4
// 1087.713 us; speedup vs baseline: 11.4679x; 1.0373x over previous
//
#include <hip/hip_runtime.h>
#include <hip/hip_bf16.h>

#define HH 512
#define VV 50257
#define TL 512
#define NT 512          // 8 waves, 2 waves/SIMD (SMT-2 latency hiding)
#define DYN_LDS 135168  // 128KB W-tiles + 2KB xbuf + 2KB ids

typedef __attribute__((ext_vector_type(8))) short short8;
typedef __attribute__((ext_vector_type(4))) float floatx4;

__device__ __forceinline__ unsigned short f2bf(float f) {
  union { float f; unsigned int u; } v; v.f = f;
  unsigned int r = (v.u + 0x7fffu + ((v.u >> 16) & 1u)) >> 16;
  return (unsigned short)r;
}
__device__ __forceinline__ float bf2f(unsigned short h) {
  union { unsigned int u; float f; } v; v.u = ((unsigned int)h) << 16;
  return v.f;
}

// ---- P1: column max of alpha_exp (+eps) ----
__global__ void colmaxK(const float* __restrict__ A, float* __restrict__ cmax) {
  __shared__ float red[4][64];
  int x = threadIdx.x & 63;
  int y = threadIdx.x >> 6;
  int c = blockIdx.x * 64 + x;
  float m = -INFINITY;
  for (int j = y; j < HH; j += 4) m = fmaxf(m, A[j * HH + c]);
  red[y][x] = m;
  __syncthreads();
  if (y == 0)
    cmax[c] = fmaxf(fmaxf(red[0][x], red[1][x]), fmaxf(red[2][x], red[3][x])) + 1e-12f;
}

// ---- P2: bf16 Wn pre-swizzled into MFMA B-fragment order ----
__global__ void buildWfK(const float* __restrict__ A, const float* __restrict__ cmax,
                         uint4* __restrict__ Wf) {
  int gid = blockIdx.x * 256 + threadIdx.x;  // 0..32767
  int T = gid >> 10;
  int k = (gid >> 6) & 15;
  int L = gid & 63;
  int n = T * 16 + (L & 15);
  int k0 = 32 * k + (L >> 4) * 8;
  float inv = 1.0f / cmax[n];
  alignas(16) unsigned short o[8];
#pragma unroll
  for (int j = 0; j < 8; ++j)
    o[j] = f2bf((A[(k0 + j) * HH + n] + 1e-12f) * inv);
  Wf[gid] = *(const uint4*)o;
}

// ---- P3: Ptab[v][n] = bf16( exp(beta[n][v]) * cmax[n] ) ----
__global__ void buildPtab(const float* __restrict__ beta, const float* __restrict__ cmax,
                          unsigned short* __restrict__ Ptab) {
  __shared__ float tile[32][33];
  int v0 = blockIdx.x * 32, h0 = blockIdx.y * 32;
  int tx = threadIdx.x, ty = threadIdx.y;
#pragma unroll
  for (int k = 0; k < 4; ++k) {
    int v = v0 + tx;
    if (v < VV) tile[ty + 8 * k][tx] = beta[(h0 + ty + 8 * k) * VV + v];
  }
  __syncthreads();
  float cm = cmax[h0 + tx];
#pragma unroll
  for (int k = 0; k < 4; ++k) {
    int v = v0 + ty + 8 * k;
    if (v < VV) Ptab[(long)v * HH + h0 + tx] = f2bf(__expf(tile[tx][ty + 8 * k]) * cm);
  }
}

// ---- Main: 64 blocks (one batch each), 8 waves = 2/SIMD (SMT-2 hides LDS latency).
// Per-CU capacity unchanged (2048 regs): wave owns 4 n-tiles x 12 reg k-tiles (192 regs)
// + acc 16; k-tiles 12..15 from LDS (128 KB/step, the shared-pipe floor).
// Lane owns exactly output n = tid: 1 Ptab load, 1 xbuf write, 1 out store per lane.
// G_t = max(stored y_{t-1}) via u16 max (bf16>=0), redundant per wave, overlapped.
__global__ __launch_bounds__(NT, 2) __attribute__((amdgpu_waves_per_eu(2, 2)))
void hmm_main(const uint4* __restrict__ Wf,
              const unsigned short* __restrict__ Ptab,
              const float* __restrict__ gamma,
              const float* __restrict__ cmax,
              const int* __restrict__ ids,
              float* __restrict__ out) {
  extern __shared__ char dls[];
  uint4* wlds = (uint4*)dls;                               // [0,131072): W k-tiles 12..15
  unsigned short* xbuf = (unsigned short*)(dls + 131072);  // [2][512] bf16
  int* ids_l = (int*)(dls + 133120);                       // [512]

  const int b = blockIdx.x, tid = threadIdx.x;
  const int w = tid >> 6, L = tid & 63;
  const int q = L >> 4;
  const long bT = (long)b * TL;

  ids_l[tid] = ids[bT + tid];

  // stage LDS-resident W k-tiles 12..15 (layout == read order)
#pragma unroll
  for (int i = 0; i < 16; ++i) {
    int e = tid + i * 512;            // 0..8191
    int Le = e & 63, r = e >> 6;
    int T = r & 31, kk = r >> 5;
    wlds[e] = Wf[(T * 16 + 12 + kk) * 64 + Le];
  }

  // register-resident W: wave w owns n-tiles 4w..4w+3, k-tiles 0..11
  short8 wa[4][12];
#pragma unroll
  for (int tau = 0; tau < 4; ++tau)
#pragma unroll
    for (int k = 0; k < 12; ++k)
      wa[tau][k] = __builtin_bit_cast(short8, Wf[((4 * w + tau) * 16 + k) * 64 + L]);

  // this lane's single output column: n = tid (tile 4w+q, col l16)
  const int n = tid;

  float A = 0.f;

  // ---- t = 0: store y_0 = u_0 raw (D_0 = 1, A = 0) ----
  {
    const int id0 = ids[bT];
    float u0 = gamma[n] * bf2f(Ptab[(long)id0 * HH + n]) / cmax[n];
    xbuf[n] = f2bf(u0);
    __syncthreads();  // also publishes wlds staging + ids_l
  }

  // Ptab prefetch pipeline: pv for step t loaded during step t-1
  int id1 = ids_l[1];
  unsigned short pvc = Ptab[(long)id1 * HH + n];

  for (int t = 1; t < TL; ++t) {
    const int pr = (t - 1) & 1, pw = t & 1;
    const int idn = ids_l[(t + 1 < TL) ? (t + 1) : t];
    const unsigned short pvn = Ptab[(long)idn * HH + n];  // for t+1

    const unsigned short* xb = xbuf + pr * 512;

    // G = max y_{t-1}: one b128 row-read + in-lane u16 max + 6 shfl (overlaps MFMA)
    short8 g8 = *(const short8*)(xb + 8 * L);
    unsigned gm = (unsigned)(unsigned short)g8[0];
#pragma unroll
    for (int j = 1; j < 8; ++j) {
      unsigned x = (unsigned)(unsigned short)g8[j];
      gm = gm > x ? gm : x;
    }
#pragma unroll
    for (int msk = 1; msk <= 32; msk <<= 1) {
      unsigned o = __shfl_xor(gm, msk);
      gm = gm > o ? gm : o;
    }
    const float G = fmaxf(bf2f((unsigned short)gm), 1e-30f);

    floatx4 acc[4];
#pragma unroll
    for (int tau = 0; tau < 4; ++tau) acc[tau] = (floatx4){0.f, 0.f, 0.f, 0.f};

    __builtin_amdgcn_s_setprio(1);  // T5: 2 waves/SIMD at different phases -> arbitration
#pragma unroll
    for (int k = 0; k < 12; ++k) {
      short8 af = *(const short8*)(xb + k * 32 + q * 8);  // quad-broadcast A rows
#pragma unroll
      for (int tau = 0; tau < 4; ++tau)
        acc[tau] = __builtin_amdgcn_mfma_f32_16x16x32_bf16(af, wa[tau][k], acc[tau], 0, 0, 0);
    }
    const uint4* wp = wlds + (4 * w) * 64 + L;
#pragma unroll
    for (int g = 0; g < 4; ++g) {
      short8 wl[4];
#pragma unroll
      for (int tau = 0; tau < 4; ++tau)
        wl[tau] = __builtin_bit_cast(short8, wp[(g * 32 + tau) * 64]);
      short8 af = *(const short8*)(xb + (12 + g) * 32 + q * 8);
#pragma unroll
      for (int tau = 0; tau < 4; ++tau)
        acc[tau] = __builtin_amdgcn_mfma_f32_16x16x32_bf16(af, wl[tau], acc[tau], 0, 0, 0);
    }
    __builtin_amdgcn_s_setprio(0);

    // lane's output: tau = q (static-index select)
    const float z = (q < 2) ? (q == 0 ? acc[0][0] : acc[1][0])
                            : (q == 2 ? acc[2][0] : acc[3][0]);
    const float un = z * bf2f(pvc);

    if (t == TL - 1) {
      out[(long)b * HH + n] = __logf(fmaxf(un, 1e-37f)) + A;
    } else {
      A += __logf(G);
      xbuf[pw * 512 + n] = f2bf(un * (1.0f / G));
    }
    pvc = pvn;
    __syncthreads();
  }
}

extern "C" void kernel_launch(void* const* d_in, const int* in_sizes, int n_in,
                              void* d_out, int out_size, void* d_ws, size_t ws_size,
                              hipStream_t stream) {
  const float* alpha_exp = (const float*)d_in[0];
  const float* beta = (const float*)d_in[1];
  const float* gamma = (const float*)d_in[2];
  const int* ids = (const int*)d_in[3];
  float* out = (float*)d_out;

  char* ws = (char*)d_ws;
  float* cmax = (float*)(ws + 0);                         // [0, 2048)
  uint4* Wf = (uint4*)(ws + 4096);                        // [4096, 528384)
  unsigned short* Ptab = (unsigned short*)(ws + 528384);  // ~51.5 MB (ws proven >= 104 MB)

  // idempotent, host-side (not a stream op; graph-capture safe), every call:
  (void)hipFuncSetAttribute((const void*)hmm_main,
                            hipFuncAttributeMaxDynamicSharedMemorySize, DYN_LDS);

  colmaxK<<<8, 256, 0, stream>>>(alpha_exp, cmax);
  buildWfK<<<128, 256, 0, stream>>>(alpha_exp, cmax, Wf);
  dim3 gT((VV + 31) / 32, HH / 32), bTd(32, 8);
  buildPtab<<<gT, bTd, 0, stream>>>(beta, cmax, Ptab);

  hmm_main<<<64, NT, DYN_LDS, stream>>>(Wf, Ptab, gamma, cmax, ids, out);
}

// Round 5
// 1019.051 us; speedup vs baseline: 12.2406x; 1.0674x over previous
//
#include <hip/hip_runtime.h>
#include <hip/hip_bf16.h>

#define HH 512
#define VV 50257
#define TL 512
#define NT 512          // 8 waves, 2 waves/SIMD
#define DYN_LDS 98304   // ~3.2 KB used; big request forces 1 block/CU

typedef __attribute__((ext_vector_type(4))) float floatx4;

__device__ __forceinline__ unsigned short f2bf(float f) {
  union { float f; unsigned int u; } v; v.f = f;
  unsigned int r = (v.u + 0x7fffu + ((v.u >> 16) & 1u)) >> 16;
  return (unsigned short)r;
}
__device__ __forceinline__ float bf2f(unsigned short h) {
  union { unsigned int u; float f; } v; v.u = ((unsigned int)h) << 16;
  return v.f;
}

// ---- P1: column max of alpha_exp (+eps) ----
__global__ void colmaxK(const float* __restrict__ A, float* __restrict__ cmax) {
  __shared__ float red[4][64];
  int x = threadIdx.x & 63;
  int y = threadIdx.x >> 6;
  int c = blockIdx.x * 64 + x;
  float m = -INFINITY;
  for (int j = y; j < HH; j += 4) m = fmaxf(m, A[j * HH + c]);
  red[y][x] = m;
  __syncthreads();
  if (y == 0)
    cmax[c] = fmaxf(fmaxf(red[0][x], red[1][x]), fmaxf(red[2][x], red[3][x])) + 1e-12f;
}

// ---- P2: fp8(e4m3) Wn pre-swizzled into MFMA B-fragment order ----
// Wf8[(T*16+k)*64 + L] = 8 bytes, byte j: Wn[32k + (L>>4)*8 + j][T*16 + (L&15)]
// Same (laneGroup,elem)->k map is used for the A (y) operand, so the contraction is
// correct for any hardware k-permutation (A/B maps mirror).
__global__ void buildWf8K(const float* __restrict__ A, const float* __restrict__ cmax,
                          uint2* __restrict__ Wf8) {
  int gid = blockIdx.x * 256 + threadIdx.x;  // 0..32767
  int T = gid >> 10;
  int k = (gid >> 6) & 15;
  int L = gid & 63;
  int n = T * 16 + (L & 15);
  int k0 = 32 * k + (L >> 4) * 8;
  float inv = 1.0f / cmax[n];
  float v0 = (A[(k0 + 0) * HH + n] + 1e-12f) * inv;
  float v1 = (A[(k0 + 1) * HH + n] + 1e-12f) * inv;
  float v2 = (A[(k0 + 2) * HH + n] + 1e-12f) * inv;
  float v3 = (A[(k0 + 3) * HH + n] + 1e-12f) * inv;
  float v4 = (A[(k0 + 4) * HH + n] + 1e-12f) * inv;
  float v5 = (A[(k0 + 5) * HH + n] + 1e-12f) * inv;
  float v6 = (A[(k0 + 6) * HH + n] + 1e-12f) * inv;
  float v7 = (A[(k0 + 7) * HH + n] + 1e-12f) * inv;
  unsigned lo, hi;
  asm("v_cvt_pk_fp8_f32 %0, %1, %2" : "=v"(lo) : "v"(v0), "v"(v1));
  asm("v_cvt_pk_fp8_f32 %0, %1, %2 op_sel:[0,0,1]" : "+v"(lo) : "v"(v2), "v"(v3));
  asm("v_cvt_pk_fp8_f32 %0, %1, %2" : "=v"(hi) : "v"(v4), "v"(v5));
  asm("v_cvt_pk_fp8_f32 %0, %1, %2 op_sel:[0,0,1]" : "+v"(hi) : "v"(v6), "v"(v7));
  Wf8[gid] = (uint2){lo, hi};
}

// ---- P3: Ptab[v][n] = bf16( exp(beta[n][v]) * cmax[n] ) ----
__global__ void buildPtab(const float* __restrict__ beta, const float* __restrict__ cmax,
                          unsigned short* __restrict__ Ptab) {
  __shared__ float tile[32][33];
  int v0 = blockIdx.x * 32, h0 = blockIdx.y * 32;
  int tx = threadIdx.x, ty = threadIdx.y;
#pragma unroll
  for (int k = 0; k < 4; ++k) {
    int v = v0 + tx;
    if (v < VV) tile[ty + 8 * k][tx] = beta[(h0 + ty + 8 * k) * VV + v];
  }
  __syncthreads();
  float cm = cmax[h0 + tx];
#pragma unroll
  for (int k = 0; k < 4; ++k) {
    int v = v0 + ty + 8 * k;
    if (v < VV) Ptab[(long)v * HH + h0 + tx] = f2bf(__expf(tile[tx][ty + 8 * k]) * cm);
  }
}

// ---- Main: 64 blocks (one batch), 8 waves (SMT-2). FULL W register-resident as fp8
// (wave: 4 n-tiles x 16 k-tiles x 8B = 128 VGPR). Zero W-LDS traffic; af reads are b64.
// fp8 y REQUIRES exact on-path rescale (any stale-max predictor has unit-circle poles
// -> stored-max random-walks out of e4m3 range): G_t = max(u_t) via 6-shfl wave reduce
// + wmx exchange, 2 barriers/step. Stored x max == 1.0; e4m3 floor flushes ~0.1% of
// z-mass. A += log G telescopes exactly.
__global__ __launch_bounds__(NT, 2) __attribute__((amdgpu_waves_per_eu(2, 2)))
void hmm_main(const long* __restrict__ Wf8,
              const unsigned short* __restrict__ Ptab,
              const float* __restrict__ gamma,
              const float* __restrict__ cmax,
              const int* __restrict__ ids,
              float* __restrict__ out) {
  extern __shared__ char dls[];
  unsigned char* xbuf = (unsigned char*)dls;   // [2][512] fp8 e4m3
  float* wmx = (float*)(dls + 1024);           // [8] per-wave maxes
  int* ids_l = (int*)(dls + 1088);             // [512]

  const int b = blockIdx.x, tid = threadIdx.x;
  const int w = tid >> 6, L = tid & 63;
  const int q = L >> 4;
  const long bT = (long)b * TL;

  ids_l[tid] = ids[bT + tid];

  // register-resident W: wave w owns n-tiles 4w..4w+3, all 16 k-tiles (128 VGPR)
  long wa[4][16];
#pragma unroll
  for (int tau = 0; tau < 4; ++tau)
#pragma unroll
    for (int k = 0; k < 16; ++k)
      wa[tau][k] = Wf8[((4 * w + tau) * 16 + k) * 64 + L];

  const int n = tid;  // lane's single output column (tile 4w+q, col L&15)
  float A;

  // ---- t = 0: x_0 = u_0 / M_0 (exact), A = log M_0 ----
  {
    const int id0 = ids[bT];
    float u0 = gamma[n] * bf2f(Ptab[(long)id0 * HH + n]) / cmax[n];
    float m = u0;
#pragma unroll
    for (int msk = 1; msk <= 32; msk <<= 1) m = fmaxf(m, __shfl_xor(m, msk));
    if (L == 0) wmx[w] = m;
    __syncthreads();
    float4 ga = *(const float4*)wmx, gb = *(const float4*)(wmx + 4);
    float M = fmaxf(fmaxf(fmaxf(ga.x, ga.y), fmaxf(ga.z, ga.w)),
                    fmaxf(fmaxf(gb.x, gb.y), fmaxf(gb.z, gb.w)));
    M = fmaxf(M, 1e-30f);
    A = __logf(M);
    float x0 = u0 / M;
    unsigned pk;
    asm("v_cvt_pk_fp8_f32 %0, %1, %2" : "=v"(pk) : "v"(x0), "v"(x0));
    xbuf[n] = (unsigned char)pk;
    __syncthreads();
  }

  // Ptab prefetch pipeline: pv for step t loaded during step t-1
  int id1 = ids_l[1];
  unsigned short pvc = Ptab[(long)id1 * HH + n];

  for (int t = 1; t < TL; ++t) {
    const int pr = (t - 1) & 1, pw = t & 1;
    const int idn = ids_l[(t + 1 < TL) ? (t + 1) : t];
    const unsigned short pvn = Ptab[(long)idn * HH + n];  // for t+1

    const unsigned char* xb = xbuf + pr * 512;

    floatx4 acc[4];
#pragma unroll
    for (int tau = 0; tau < 4; ++tau) acc[tau] = (floatx4){0.f, 0.f, 0.f, 0.f};

    __builtin_amdgcn_s_setprio(1);
#pragma unroll
    for (int k = 0; k < 16; ++k) {
      long af = *(const long*)(xb + k * 32 + q * 8);  // quad-broadcast y slice, b64
#pragma unroll
      for (int tau = 0; tau < 4; ++tau)
        acc[tau] = __builtin_amdgcn_mfma_f32_16x16x32_fp8_fp8(af, wa[tau][k], acc[tau], 0, 0, 0);
    }
    __builtin_amdgcn_s_setprio(0);

    const float z = (q < 2) ? (q == 0 ? acc[0][0] : acc[1][0])
                            : (q == 2 ? acc[2][0] : acc[3][0]);
    const float un = z * bf2f(pvc);

    if (t == TL - 1) {
      out[(long)b * HH + n] = __logf(fmaxf(un, 1e-37f)) + A;
    } else {
      // exact on-path global max of u_t
      float m = un;
#pragma unroll
      for (int msk = 1; msk <= 32; msk <<= 1) m = fmaxf(m, __shfl_xor(m, msk));
      if (L == 0) wmx[w] = m;
      __syncthreads();
      float4 ga = *(const float4*)wmx, gb = *(const float4*)(wmx + 4);
      float G = fmaxf(fmaxf(fmaxf(ga.x, ga.y), fmaxf(ga.z, ga.w)),
                      fmaxf(fmaxf(gb.x, gb.y), fmaxf(gb.z, gb.w)));
      G = fmaxf(G, 1e-30f);
      A += __logf(G);
      float x = un * (1.0f / G);  // in [0,1], max exactly 1.0
      unsigned pk;
      asm("v_cvt_pk_fp8_f32 %0, %1, %2" : "=v"(pk) : "v"(x), "v"(x));
      xbuf[pw * 512 + n] = (unsigned char)pk;
      __syncthreads();
    }
    pvc = pvn;
  }
}

extern "C" void kernel_launch(void* const* d_in, const int* in_sizes, int n_in,
                              void* d_out, int out_size, void* d_ws, size_t ws_size,
                              hipStream_t stream) {
  const float* alpha_exp = (const float*)d_in[0];
  const float* beta = (const float*)d_in[1];
  const float* gamma = (const float*)d_in[2];
  const int* ids = (const int*)d_in[3];
  float* out = (float*)d_out;

  char* ws = (char*)d_ws;
  float* cmax = (float*)(ws + 0);                         // [0, 2048)
  uint2* Wf8 = (uint2*)(ws + 4096);                       // [4096, 266240) 256 KB
  unsigned short* Ptab = (unsigned short*)(ws + 528384);  // ~51.5 MB (ws proven >= 104 MB)

  // idempotent, host-side (not a stream op; graph-capture safe), every call:
  (void)hipFuncSetAttribute((const void*)hmm_main,
                            hipFuncAttributeMaxDynamicSharedMemorySize, DYN_LDS);

  colmaxK<<<8, 256, 0, stream>>>(alpha_exp, cmax);
  buildWf8K<<<128, 256, 0, stream>>>(alpha_exp, cmax, Wf8);
  dim3 gT((VV + 31) / 32, HH / 32), bTd(32, 8);
  buildPtab<<<gT, bTd, 0, stream>>>(beta, cmax, Ptab);

  hmm_main<<<64, NT, DYN_LDS, stream>>>((const long*)Wf8, Ptab, gamma, cmax, ids, out);
}

// Round 6
// 673.864 us; speedup vs baseline: 18.5108x; 1.5122x over previous
//
#include <hip/hip_runtime.h>
#include <hip/hip_bf16.h>

#define HH 512
#define VV 50257
#define TL 512
#define NT 512          // 8 waves, 2 waves/SIMD
#define DYN_LDS 98304   // ~3.2 KB used; big request forces 1 block/CU

typedef __attribute__((ext_vector_type(4))) float floatx4;
typedef __attribute__((ext_vector_type(8))) int intx8;

__device__ __forceinline__ unsigned short f2bf(float f) {
  union { float f; unsigned int u; } v; v.f = f;
  unsigned int r = (v.u + 0x7fffu + ((v.u >> 16) & 1u)) >> 16;
  return (unsigned short)r;
}
__device__ __forceinline__ float bf2f(unsigned short h) {
  union { unsigned int u; float f; } v; v.u = ((unsigned int)h) << 16;
  return v.f;
}

// wave64 max via DPP (all VALU, no LDS): xor1,xor2 (quad_perm), xor4 (half_mirror),
// xor8 (mirror), then bcast15/bcast31 accumulate into lane 63; readlane broadcasts.
__device__ __forceinline__ float wave_max_dpp(float x) {
  int xi = __builtin_bit_cast(int, x);
#define DPPSTEP(ctrl)                                                              \
  {                                                                                \
    int yi = __builtin_amdgcn_update_dpp(xi, xi, (ctrl), 0xf, 0xf, false);         \
    float a = __builtin_bit_cast(float, xi), b = __builtin_bit_cast(float, yi);    \
    xi = __builtin_bit_cast(int, fmaxf(a, b));                                     \
  }
  DPPSTEP(0xB1)   // quad_perm [1,0,3,2]
  DPPSTEP(0x4E)   // quad_perm [2,3,0,1]
  DPPSTEP(0x141)  // row_half_mirror (xor4 once quads uniform)
  DPPSTEP(0x140)  // row_mirror      (xor8 once 8-groups uniform)
  DPPSTEP(0x142)  // row_bcast15 -> lanes 16.. get lower-row max
  DPPSTEP(0x143)  // row_bcast31 -> lane 63 = global max
#undef DPPSTEP
  return __builtin_bit_cast(float, __builtin_amdgcn_readlane(xi, 63));
}

// ---- P1: column max of alpha_exp (+eps) ----
__global__ void colmaxK(const float* __restrict__ A, float* __restrict__ cmax) {
  __shared__ float red[4][64];
  int x = threadIdx.x & 63;
  int y = threadIdx.x >> 6;
  int c = blockIdx.x * 64 + x;
  float m = -INFINITY;
  for (int j = y; j < HH; j += 4) m = fmaxf(m, A[j * HH + c]);
  red[y][x] = m;
  __syncthreads();
  if (y == 0)
    cmax[c] = fmaxf(fmaxf(red[0][x], red[1][x]), fmaxf(red[2][x], red[3][x])) + 1e-12f;
}

// ---- P2: fp8 Wn pre-swizzled for mfma_scale 16x16x128 (B-fragment order) ----
// Wf8s[(T*4+kk)*64+L] = 32 bytes, byte (4d+j): Wn[kk*128 + (L>>4)*32 + 4d+j][T*16+(L&15)]
// A (y) operand uses the SAME (laneGroup,byte)->k map, so any HW k-permutation cancels
// (A/B fragment layouts mirror); all scales are 1.0 so scale-block mapping is moot.
__global__ void buildWf8sK(const float* __restrict__ A, const float* __restrict__ cmax,
                           intx8* __restrict__ Wf8s) {
  int gid = blockIdx.x * 256 + threadIdx.x;  // 0..8191
  int L = gid & 63, r = gid >> 6;            // r = T*4 + kk
  int kk = r & 3, T = r >> 2;
  int n = T * 16 + (L & 15);
  int kbase = kk * 128 + (L >> 4) * 32;
  float inv = 1.0f / cmax[n];
  intx8 o;
#pragma unroll
  for (int d = 0; d < 8; ++d) {
    float v0 = (A[(kbase + 4 * d + 0) * HH + n] + 1e-12f) * inv;
    float v1 = (A[(kbase + 4 * d + 1) * HH + n] + 1e-12f) * inv;
    float v2 = (A[(kbase + 4 * d + 2) * HH + n] + 1e-12f) * inv;
    float v3 = (A[(kbase + 4 * d + 3) * HH + n] + 1e-12f) * inv;
    unsigned pk;
    asm("v_cvt_pk_fp8_f32 %0, %1, %2" : "=v"(pk) : "v"(v0), "v"(v1));
    asm("v_cvt_pk_fp8_f32 %0, %1, %2 op_sel:[0,0,1]" : "+v"(pk) : "v"(v2), "v"(v3));
    o[d] = (int)pk;
  }
  Wf8s[gid] = o;
}

// ---- P3: Ptab[v][n] = bf16( exp(beta[n][v]) * cmax[n] ) ----
__global__ void buildPtab(const float* __restrict__ beta, const float* __restrict__ cmax,
                          unsigned short* __restrict__ Ptab) {
  __shared__ float tile[32][33];
  int v0 = blockIdx.x * 32, h0 = blockIdx.y * 32;
  int tx = threadIdx.x, ty = threadIdx.y;
#pragma unroll
  for (int k = 0; k < 4; ++k) {
    int v = v0 + tx;
    if (v < VV) tile[ty + 8 * k][tx] = beta[(h0 + ty + 8 * k) * VV + v];
  }
  __syncthreads();
  float cm = cmax[h0 + tx];
#pragma unroll
  for (int k = 0; k < 4; ++k) {
    int v = v0 + ty + 8 * k;
    if (v < VV) Ptab[(long)v * HH + h0 + tx] = f2bf(__expf(tile[tx][ty + 8 * k]) * cm);
  }
}

// ---- Main: 64 blocks (one batch), 8 waves. W fully register-resident as fp8 in
// 16x16x128 MX order (wave: 4 n-tiles x 4 k-steps x 32B = 128 VGPR). 16 MFMA/wave/step.
// Critical-path fixes this round:
//  (1) raw s_barrier + lgkmcnt-only waits -> Ptab HBM prefetch no longer drained by
//      the barrier's implicit vmcnt(0) every step (was ~900cy/step on the spine);
//  (2) DPP wave-max (VALU) replaces 6 dependent ds-shuffles (~700cy -> ~60cy);
//  (3) K=128 scaled MFMA halves matrix-pipe issue (620 -> ~276 cy/SIMD/step).
// Exact on-path rescale kept (fp8 range requires it): G_t = max(u_t), x max == 1.0.
__global__ __launch_bounds__(NT, 2) __attribute__((amdgpu_waves_per_eu(2, 2)))
void hmm_main(const intx8* __restrict__ Wf8s,
              const unsigned short* __restrict__ Ptab,
              const float* __restrict__ gamma,
              const float* __restrict__ cmax,
              const int* __restrict__ ids,
              float* __restrict__ out) {
  extern __shared__ char dls[];
  unsigned char* xbuf = (unsigned char*)dls;   // [2][512] fp8 e4m3
  float* wmx = (float*)(dls + 1024);           // [8] per-wave maxes
  int* ids_l = (int*)(dls + 1088);             // [512]

  const int b = blockIdx.x, tid = threadIdx.x;
  const int w = tid >> 6, L = tid & 63;
  const int q = L >> 4;
  const long bT = (long)b * TL;

  ids_l[tid] = ids[bT + tid];

  // register-resident W: wave w owns n-tiles 4w..4w+3, all 4 k-steps (128 VGPR)
  intx8 wa[4][4];
#pragma unroll
  for (int tau = 0; tau < 4; ++tau)
#pragma unroll
    for (int kk = 0; kk < 4; ++kk)
      wa[tau][kk] = Wf8s[((4 * w + tau) * 4 + kk) * 64 + L];

  const int n = tid;  // lane's single output column (tile 4w+q, col L&15)
  float A;

  // ---- t = 0: x_0 = u_0 / M_0 (exact), A = log M_0 ----
  {
    const int id0 = ids[bT];
    float u0 = gamma[n] * bf2f(Ptab[(long)id0 * HH + n]) / cmax[n];
    float m = wave_max_dpp(u0);
    if (L == 0) wmx[w] = m;
    __syncthreads();
    float4 ga = *(const float4*)wmx, gb = *(const float4*)(wmx + 4);
    float M = fmaxf(fmaxf(fmaxf(ga.x, ga.y), fmaxf(ga.z, ga.w)),
                    fmaxf(fmaxf(gb.x, gb.y), fmaxf(gb.z, gb.w)));
    M = fmaxf(M, 1e-30f);
    A = __logf(M);
    float x0 = u0 * __builtin_amdgcn_rcpf(M);
    unsigned pk;
    asm("v_cvt_pk_fp8_f32 %0, %1, %2" : "=v"(pk) : "v"(x0), "v"(x0));
    xbuf[n] = (unsigned char)(pk & 0xff);
    __syncthreads();
  }

  // Ptab prefetch pipeline: pv for step t loaded during step t-1 (rides across raw barriers)
  unsigned short pvc = Ptab[(long)ids_l[1] * HH + n];

  for (int t = 1; t < TL; ++t) {
    const int idn = ids_l[(t + 1 < TL) ? (t + 1) : t];
    const unsigned short pvn = Ptab[(long)idn * HH + n];  // for t+1

    const unsigned char* xb = xbuf + ((t - 1) & 1) * 512;

    floatx4 acc[4];
#pragma unroll
    for (int tau = 0; tau < 4; ++tau) acc[tau] = (floatx4){0.f, 0.f, 0.f, 0.f};

    __builtin_amdgcn_s_setprio(1);
#pragma unroll
    for (int kk = 0; kk < 4; ++kk) {
      intx8 af = *(const intx8*)(xb + kk * 128 + q * 32);  // quad-broadcast y slice
#pragma unroll
      for (int tau = 0; tau < 4; ++tau)
        acc[tau] = __builtin_amdgcn_mfma_scale_f32_16x16x128_f8f6f4(
            af, wa[tau][kk], acc[tau], 0, 0, 0, 0x7F7F7F7F, 0, 0x7F7F7F7F);
    }
    __builtin_amdgcn_s_setprio(0);

    const float z = (q < 2) ? (q == 0 ? acc[0][0] : acc[1][0])
                            : (q == 2 ? acc[2][0] : acc[3][0]);
    const float un = z * bf2f(pvc);

    if (t == TL - 1) {
      out[(long)b * HH + n] = __logf(fmaxf(un, 1e-37f)) + A;
    } else {
      float m = wave_max_dpp(un);            // VALU-only wave reduce
      if (L == 0) wmx[w] = m;
      asm volatile("s_waitcnt lgkmcnt(0)" ::: "memory");  // LDS-only drain (vmcnt rides)
      __builtin_amdgcn_s_barrier();
      __builtin_amdgcn_sched_barrier(0);
      float4 ga = *(const float4*)wmx, gb = *(const float4*)(wmx + 4);
      float G = fmaxf(fmaxf(fmaxf(ga.x, ga.y), fmaxf(ga.z, ga.w)),
                      fmaxf(fmaxf(gb.x, gb.y), fmaxf(gb.z, gb.w)));
      G = fmaxf(G, 1e-30f);
      A += __logf(G);                        // off critical path (feeds only output)
      float x = un * __builtin_amdgcn_rcpf(G);
      unsigned pk;
      asm("v_cvt_pk_fp8_f32 %0, %1, %2" : "=v"(pk) : "v"(x), "v"(x));
      xbuf[(t & 1) * 512 + n] = (unsigned char)(pk & 0xff);
      asm volatile("s_waitcnt lgkmcnt(0)" ::: "memory");
      __builtin_amdgcn_s_barrier();
      __builtin_amdgcn_sched_barrier(0);
    }
    pvc = pvn;
  }
}

extern "C" void kernel_launch(void* const* d_in, const int* in_sizes, int n_in,
                              void* d_out, int out_size, void* d_ws, size_t ws_size,
                              hipStream_t stream) {
  const float* alpha_exp = (const float*)d_in[0];
  const float* beta = (const float*)d_in[1];
  const float* gamma = (const float*)d_in[2];
  const int* ids = (const int*)d_in[3];
  float* out = (float*)d_out;

  char* ws = (char*)d_ws;
  float* cmax = (float*)(ws + 0);                         // [0, 2048)
  intx8* Wf8s = (intx8*)(ws + 4096);                      // [4096, 266240) 256 KB
  unsigned short* Ptab = (unsigned short*)(ws + 528384);  // ~51.5 MB (ws proven >= 104 MB)

  // idempotent, host-side (not a stream op; graph-capture safe), every call:
  (void)hipFuncSetAttribute((const void*)hmm_main,
                            hipFuncAttributeMaxDynamicSharedMemorySize, DYN_LDS);

  colmaxK<<<8, 256, 0, stream>>>(alpha_exp, cmax);
  buildWf8sK<<<32, 256, 0, stream>>>(alpha_exp, cmax, Wf8s);
  dim3 gT((VV + 31) / 32, HH / 32), bTd(32, 8);
  buildPtab<<<gT, bTd, 0, stream>>>(beta, cmax, Ptab);

  hmm_main<<<64, NT, DYN_LDS, stream>>>(Wf8s, Ptab, gamma, cmax, ids, out);
}

// Round 7
// 623.909 us; speedup vs baseline: 19.9929x; 1.0801x over previous
//
#include <hip/hip_runtime.h>
#include <hip/hip_bf16.h>

#define HH 512
#define VV 50257
#define TL 512
#define NT 512          // 8 waves, 2 waves/SIMD
#define DYN_LDS 98304   // ~3.2 KB used; big request forces 1 block/CU

typedef __attribute__((ext_vector_type(4))) float floatx4;
typedef __attribute__((ext_vector_type(8))) int intx8;

__device__ __forceinline__ unsigned short f2bf(float f) {
  union { float f; unsigned int u; } v; v.f = f;
  unsigned int r = (v.u + 0x7fffu + ((v.u >> 16) & 1u)) >> 16;
  return (unsigned short)r;
}
__device__ __forceinline__ float bf2f(unsigned short h) {
  union { unsigned int u; float f; } v; v.u = ((unsigned int)h) << 16;
  return v.f;
}

// wave64 max via DPP (all VALU, no LDS); lane63 ends with global max, readlane bcasts.
__device__ __forceinline__ float wave_max_dpp(float x) {
  int xi = __builtin_bit_cast(int, x);
#define DPPSTEP(ctrl)                                                              \
  {                                                                                \
    int yi = __builtin_amdgcn_update_dpp(xi, xi, (ctrl), 0xf, 0xf, false);         \
    float a = __builtin_bit_cast(float, xi), b = __builtin_bit_cast(float, yi);    \
    xi = __builtin_bit_cast(int, fmaxf(a, b));                                     \
  }
  DPPSTEP(0xB1)   // quad_perm [1,0,3,2]
  DPPSTEP(0x4E)   // quad_perm [2,3,0,1]
  DPPSTEP(0x141)  // row_half_mirror
  DPPSTEP(0x140)  // row_mirror
  DPPSTEP(0x142)  // row_bcast15
  DPPSTEP(0x143)  // row_bcast31 -> lane 63 = global max
#undef DPPSTEP
  return __builtin_bit_cast(float, __builtin_amdgcn_readlane(xi, 63));
}

// ---- P1: column max of alpha_exp (+eps) ----
__global__ void colmaxK(const float* __restrict__ A, float* __restrict__ cmax) {
  __shared__ float red[4][64];
  int x = threadIdx.x & 63;
  int y = threadIdx.x >> 6;
  int c = blockIdx.x * 64 + x;
  float m = -INFINITY;
  for (int j = y; j < HH; j += 4) m = fmaxf(m, A[j * HH + c]);
  red[y][x] = m;
  __syncthreads();
  if (y == 0)
    cmax[c] = fmaxf(fmaxf(red[0][x], red[1][x]), fmaxf(red[2][x], red[3][x])) + 1e-12f;
}

// ---- P2: fp8 Wn pre-swizzled for mfma_scale 16x16x128 (B-fragment order) ----
__global__ void buildWf8sK(const float* __restrict__ A, const float* __restrict__ cmax,
                           intx8* __restrict__ Wf8s) {
  int gid = blockIdx.x * 256 + threadIdx.x;  // 0..8191
  int L = gid & 63, r = gid >> 6;            // r = T*4 + kk
  int kk = r & 3, T = r >> 2;
  int n = T * 16 + (L & 15);
  int kbase = kk * 128 + (L >> 4) * 32;
  float inv = 1.0f / cmax[n];
  intx8 o;
#pragma unroll
  for (int d = 0; d < 8; ++d) {
    float v0 = (A[(kbase + 4 * d + 0) * HH + n] + 1e-12f) * inv;
    float v1 = (A[(kbase + 4 * d + 1) * HH + n] + 1e-12f) * inv;
    float v2 = (A[(kbase + 4 * d + 2) * HH + n] + 1e-12f) * inv;
    float v3 = (A[(kbase + 4 * d + 3) * HH + n] + 1e-12f) * inv;
    unsigned pk;
    asm("v_cvt_pk_fp8_f32 %0, %1, %2" : "=v"(pk) : "v"(v0), "v"(v1));
    asm("v_cvt_pk_fp8_f32 %0, %1, %2 op_sel:[0,0,1]" : "+v"(pk) : "v"(v2), "v"(v3));
    o[d] = (int)pk;
  }
  Wf8s[gid] = o;
}

// ---- P3: Ptab[v][n] = bf16( exp(beta[n][v]) * cmax[n] ) ----
__global__ void buildPtab(const float* __restrict__ beta, const float* __restrict__ cmax,
                          unsigned short* __restrict__ Ptab) {
  __shared__ float tile[32][33];
  int v0 = blockIdx.x * 32, h0 = blockIdx.y * 32;
  int tx = threadIdx.x, ty = threadIdx.y;
#pragma unroll
  for (int k = 0; k < 4; ++k) {
    int v = v0 + tx;
    if (v < VV) tile[ty + 8 * k][tx] = beta[(h0 + ty + 8 * k) * VV + v];
  }
  __syncthreads();
  float cm = cmax[h0 + tx];
#pragma unroll
  for (int k = 0; k < 4; ++k) {
    int v = v0 + ty + 8 * k;
    if (v < VV) Ptab[(long)v * HH + h0 + tx] = f2bf(__expf(tile[tx][ty + 8 * k]) * cm);
  }
}

// ---- Main: 64 blocks, 8 waves. W register-resident fp8 MX order (128 regs/lane).
// ONE barrier/step: per-wave exponent normalization (stored x = un*2^-e_w, max in [1,2))
// with the cross-wave scale correction folded into the MFMA's per-32-block A-scales:
//   k-block b of kk covers wave wv = 2kk + (b>>1); scale byte = 127 + e_wv - E, E = max e.
//   A += E*ln2 (exact). Zero-memory conditioning; per-region fp8 precision >= global-G.
// Depth-2 xbuf/elds + barrier-per-iter bounds wave skew to 1 step (race-free).
__global__ __launch_bounds__(NT, 2) __attribute__((amdgpu_waves_per_eu(2, 2)))
void hmm_main(const intx8* __restrict__ Wf8s,
              const unsigned short* __restrict__ Ptab,
              const float* __restrict__ gamma,
              const float* __restrict__ cmax,
              const int* __restrict__ ids,
              float* __restrict__ out) {
  extern __shared__ char dls[];
  unsigned char* xbuf = (unsigned char*)dls;   // [2][512] fp8 e4m3 (per-wave normalized)
  int* elds = (int*)(dls + 1024);              // [2][8] per-wave exponents
  int* ids_l = (int*)(dls + 1088);             // [512]

  const int b = blockIdx.x, tid = threadIdx.x;
  const int w = tid >> 6, L = tid & 63;
  const int q = L >> 4;
  const long bT = (long)b * TL;

  ids_l[tid] = ids[bT + tid];

  // register-resident W: wave w owns n-tiles 4w..4w+3, all 4 k-steps (128 regs)
  intx8 wa[4][4];
#pragma unroll
  for (int tau = 0; tau < 4; ++tau)
#pragma unroll
    for (int kk = 0; kk < 4; ++kk)
      wa[tau][kk] = Wf8s[((4 * w + tau) * 4 + kk) * 64 + L];

  const int n = tid;  // lane's single output column (tile 4w+q, col L&15)
  float A = 0.f;

  // ---- t = 0: x_0 = u_0 * 2^-e_w (per-wave normalized), publish e_w ----
  {
    const int id0 = ids[bT];
    float u0 = gamma[n] * bf2f(Ptab[(long)id0 * HH + n]) / cmax[n];
    float m = wave_max_dpp(u0);
    int ebits = (__builtin_bit_cast(int, m) >> 23) & 0xFF;
    float nf = __builtin_bit_cast(float, (254 - ebits) << 23);  // 2^-(ebits-127)
    float x0 = u0 * nf;
    unsigned pk;
    asm("v_cvt_pk_fp8_f32 %0, %1, %2" : "=v"(pk) : "v"(x0), "v"(x0));
    xbuf[n] = (unsigned char)(pk & 0xff);
    if (L == 0) elds[w] = ebits - 127;
    __syncthreads();  // also publishes ids_l
  }

  unsigned short pvc = Ptab[(long)ids_l[1] * HH + n];

  for (int t = 1; t < TL; ++t) {
    const int idn = ids_l[(t + 1 < TL) ? (t + 1) : t];
    const unsigned short pvn = Ptab[(long)idn * HH + n];  // prefetch, rides over barrier

    const int pr = (t - 1) & 1;
    const unsigned char* xb = xbuf + pr * 512;

    // read per-wave exponents; E = max; per-kk scale words (uniform per wave)
    int4 ea = *(const int4*)&elds[pr * 8];
    int4 eb = *(const int4*)&elds[pr * 8 + 4];
    int E = max(max(max(ea.x, ea.y), max(ea.z, ea.w)),
                max(max(eb.x, eb.y), max(eb.z, eb.w)));
    A += (float)E * 0.69314718056f;
    const int s0 = max(127 + ea.x - E, 0), s1 = max(127 + ea.y - E, 0);
    const int s2 = max(127 + ea.z - E, 0), s3 = max(127 + ea.w - E, 0);
    const int s4 = max(127 + eb.x - E, 0), s5 = max(127 + eb.y - E, 0);
    const int s6 = max(127 + eb.z - E, 0), s7 = max(127 + eb.w - E, 0);
    const int sa0 = s0 * 0x0101 + s1 * 0x01010000;
    const int sa1 = s2 * 0x0101 + s3 * 0x01010000;
    const int sa2 = s4 * 0x0101 + s5 * 0x01010000;
    const int sa3 = s6 * 0x0101 + s7 * 0x01010000;

    intx8 af0 = *(const intx8*)(xb + 0 * 128 + q * 32);
    intx8 af1 = *(const intx8*)(xb + 1 * 128 + q * 32);
    intx8 af2 = *(const intx8*)(xb + 2 * 128 + q * 32);
    intx8 af3 = *(const intx8*)(xb + 3 * 128 + q * 32);

    floatx4 acc[4];
#pragma unroll
    for (int tau = 0; tau < 4; ++tau) acc[tau] = (floatx4){0.f, 0.f, 0.f, 0.f};

    __builtin_amdgcn_s_setprio(1);
#pragma unroll
    for (int tau = 0; tau < 4; ++tau) {
      acc[tau] = __builtin_amdgcn_mfma_scale_f32_16x16x128_f8f6f4(
          af0, wa[tau][0], acc[tau], 0, 0, 0, sa0, 0, 0x7F7F7F7F);
      acc[tau] = __builtin_amdgcn_mfma_scale_f32_16x16x128_f8f6f4(
          af1, wa[tau][1], acc[tau], 0, 0, 0, sa1, 0, 0x7F7F7F7F);
      acc[tau] = __builtin_amdgcn_mfma_scale_f32_16x16x128_f8f6f4(
          af2, wa[tau][2], acc[tau], 0, 0, 0, sa2, 0, 0x7F7F7F7F);
      acc[tau] = __builtin_amdgcn_mfma_scale_f32_16x16x128_f8f6f4(
          af3, wa[tau][3], acc[tau], 0, 0, 0, sa3, 0, 0x7F7F7F7F);
    }
    __builtin_amdgcn_s_setprio(0);

    const float z = (q < 2) ? (q == 0 ? acc[0][0] : acc[1][0])
                            : (q == 2 ? acc[2][0] : acc[3][0]);
    const float un = z * bf2f(pvc);

    if (t == TL - 1) {
      out[(long)b * HH + n] = __logf(fmaxf(un, 1e-37f)) + A;
    } else {
      float m = wave_max_dpp(un);
      int ebits = (__builtin_bit_cast(int, m) >> 23) & 0xFF;
      float nf = __builtin_bit_cast(float, (254 - ebits) << 23);
      float x = un * nf;  // per-wave normalized, max in [1,2)
      unsigned pk;
      asm("v_cvt_pk_fp8_f32 %0, %1, %2" : "=v"(pk) : "v"(x), "v"(x));
      xbuf[(t & 1) * 512 + n] = (unsigned char)(pk & 0xff);
      if (L == 0) elds[(t & 1) * 8 + w] = ebits - 127;
      asm volatile("s_waitcnt lgkmcnt(0)" ::: "memory");  // LDS-only drain (vmcnt rides)
      __builtin_amdgcn_s_barrier();
      __builtin_amdgcn_sched_barrier(0);
    }
    pvc = pvn;
  }
}

extern "C" void kernel_launch(void* const* d_in, const int* in_sizes, int n_in,
                              void* d_out, int out_size, void* d_ws, size_t ws_size,
                              hipStream_t stream) {
  const float* alpha_exp = (const float*)d_in[0];
  const float* beta = (const float*)d_in[1];
  const float* gamma = (const float*)d_in[2];
  const int* ids = (const int*)d_in[3];
  float* out = (float*)d_out;

  char* ws = (char*)d_ws;
  float* cmax = (float*)(ws + 0);                         // [0, 2048)
  intx8* Wf8s = (intx8*)(ws + 4096);                      // [4096, 266240) 256 KB
  unsigned short* Ptab = (unsigned short*)(ws + 528384);  // ~51.5 MB (ws proven >= 104 MB)

  // idempotent, host-side (not a stream op; graph-capture safe), every call:
  (void)hipFuncSetAttribute((const void*)hmm_main,
                            hipFuncAttributeMaxDynamicSharedMemorySize, DYN_LDS);

  colmaxK<<<8, 256, 0, stream>>>(alpha_exp, cmax);
  buildWf8sK<<<32, 256, 0, stream>>>(alpha_exp, cmax, Wf8s);
  dim3 gT((VV + 31) / 32, HH / 32), bTd(32, 8);
  buildPtab<<<gT, bTd, 0, stream>>>(beta, cmax, Ptab);

  hmm_main<<<64, NT, DYN_LDS, stream>>>(Wf8s, Ptab, gamma, cmax, ids, out);
}

// Round 8
// 619.452 us; speedup vs baseline: 20.1368x; 1.0072x over previous
//
#include <hip/hip_runtime.h>
#include <hip/hip_bf16.h>

#define HH 512
#define VV 50257
#define TL 512
#define NT 256          // 4 waves, 1 wave/SIMD; W fully register-resident per wave
#define DYN_LDS 98304   // ~3.1 KB used; big request keeps the CU exclusive

typedef __attribute__((ext_vector_type(4))) float floatx4;
typedef __attribute__((ext_vector_type(8))) int intx8;

__device__ __forceinline__ unsigned short f2bf(float f) {
  union { float f; unsigned int u; } v; v.f = f;
  unsigned int r = (v.u + 0x7fffu + ((v.u >> 16) & 1u)) >> 16;
  return (unsigned short)r;
}
__device__ __forceinline__ float bf2f(unsigned short h) {
  union { unsigned int u; float f; } v; v.u = ((unsigned int)h) << 16;
  return v.f;
}

// wave64 max via DPP (all VALU, no LDS); lane63 ends with global max, readlane bcasts.
__device__ __forceinline__ float wave_max_dpp(float x) {
  int xi = __builtin_bit_cast(int, x);
#define DPPSTEP(ctrl)                                                              \
  {                                                                                \
    int yi = __builtin_amdgcn_update_dpp(xi, xi, (ctrl), 0xf, 0xf, false);         \
    float a = __builtin_bit_cast(float, xi), b = __builtin_bit_cast(float, yi);    \
    xi = __builtin_bit_cast(int, fmaxf(a, b));                                     \
  }
  DPPSTEP(0xB1)   // quad_perm [1,0,3,2]
  DPPSTEP(0x4E)   // quad_perm [2,3,0,1]
  DPPSTEP(0x141)  // row_half_mirror
  DPPSTEP(0x140)  // row_mirror
  DPPSTEP(0x142)  // row_bcast15
  DPPSTEP(0x143)  // row_bcast31 -> lane 63 = global max
#undef DPPSTEP
  return __builtin_bit_cast(float, __builtin_amdgcn_readlane(xi, 63));
}

// ---- P1: column max of alpha_exp (+eps) ----
__global__ void colmaxK(const float* __restrict__ A, float* __restrict__ cmax) {
  __shared__ float red[4][64];
  int x = threadIdx.x & 63;
  int y = threadIdx.x >> 6;
  int c = blockIdx.x * 64 + x;
  float m = -INFINITY;
  for (int j = y; j < HH; j += 4) m = fmaxf(m, A[j * HH + c]);
  red[y][x] = m;
  __syncthreads();
  if (y == 0)
    cmax[c] = fmaxf(fmaxf(red[0][x], red[1][x]), fmaxf(red[2][x], red[3][x])) + 1e-12f;
}

// ---- P2: fp8 Wn pre-swizzled for mfma_scale 16x16x128 (B-fragment order) ----
__global__ void buildWf8sK(const float* __restrict__ A, const float* __restrict__ cmax,
                           intx8* __restrict__ Wf8s) {
  int gid = blockIdx.x * 256 + threadIdx.x;  // 0..8191
  int L = gid & 63, r = gid >> 6;            // r = T*4 + kk
  int kk = r & 3, T = r >> 2;
  int n = T * 16 + (L & 15);
  int kbase = kk * 128 + (L >> 4) * 32;
  float inv = 1.0f / cmax[n];
  intx8 o;
#pragma unroll
  for (int d = 0; d < 8; ++d) {
    float v0 = (A[(kbase + 4 * d + 0) * HH + n] + 1e-12f) * inv;
    float v1 = (A[(kbase + 4 * d + 1) * HH + n] + 1e-12f) * inv;
    float v2 = (A[(kbase + 4 * d + 2) * HH + n] + 1e-12f) * inv;
    float v3 = (A[(kbase + 4 * d + 3) * HH + n] + 1e-12f) * inv;
    unsigned pk;
    asm("v_cvt_pk_fp8_f32 %0, %1, %2" : "=v"(pk) : "v"(v0), "v"(v1));
    asm("v_cvt_pk_fp8_f32 %0, %1, %2 op_sel:[0,0,1]" : "+v"(pk) : "v"(v2), "v"(v3));
    o[d] = (int)pk;
  }
  Wf8s[gid] = o;
}

// ---- P3: Ptab[v][n] = bf16( exp(beta[n][v]) * cmax[n] ) ----
__global__ void buildPtab(const float* __restrict__ beta, const float* __restrict__ cmax,
                          unsigned short* __restrict__ Ptab) {
  __shared__ float tile[32][33];
  int v0 = blockIdx.x * 32, h0 = blockIdx.y * 32;
  int tx = threadIdx.x, ty = threadIdx.y;
#pragma unroll
  for (int k = 0; k < 4; ++k) {
    int v = v0 + tx;
    if (v < VV) tile[ty + 8 * k][tx] = beta[(h0 + ty + 8 * k) * VV + v];
  }
  __syncthreads();
  float cm = cmax[h0 + tx];
#pragma unroll
  for (int k = 0; k < 4; ++k) {
    int v = v0 + ty + 8 * k;
    if (v < VV) Ptab[(long)v * HH + h0 + tx] = f2bf(__expf(tile[tx][ty + 8 * k]) * cm);
  }
}

// ---- Main: 64 blocks, 4 waves (1/SIMD). Wave w owns n in [128w,128w+128): 8 n-tiles x
// 4 kk x 32B fp8 = 256 VGPR of W, fully register-resident. Per step per wave: 32 MFMA
// (kk-outer, tau-inner -> dependent pairs 8 insts apart, no stalls), 8 af ds_read_b128,
// 1 elds b32, 2 b8 writes, 1 barrier. kk-chunk == wave kk's output domain -> uniform
// per-kk MX scale byte = ub_kk - maxub + 127 (exponents as raw fp32 ebits bytes).
// A += (maxub-127)*ln2 per step. Depth-2 xbuf/elds + 1 barrier/iter = race-free.
__global__ __launch_bounds__(NT, 1) __attribute__((amdgpu_waves_per_eu(1, 1)))
void hmm_main(const intx8* __restrict__ Wf8s,
              const unsigned short* __restrict__ Ptab,
              const float* __restrict__ gamma,
              const float* __restrict__ cmax,
              const int* __restrict__ ids,
              float* __restrict__ out) {
  extern __shared__ char dls[];
  unsigned char* xbuf = (unsigned char*)dls;            // [2][512] fp8 (per-wave norm)
  unsigned char* eldsb = (unsigned char*)(dls + 1024);  // [2][4] exponent bytes
  int* ids_l = (int*)(dls + 1040);                      // [512]

  const int b = blockIdx.x, tid = threadIdx.x;
  const int w = tid >> 6, L = tid & 63;
  const int q = L >> 4, l16 = L & 15;
  const long bT = (long)b * TL;

  ids_l[tid] = ids[bT + tid];
  ids_l[tid + 256] = ids[bT + tid + 256];

  // register-resident W: wave w owns n-tiles 8w..8w+7, all 4 kk (256 VGPR)
  intx8 wa[8][4];
#pragma unroll
  for (int tau = 0; tau < 8; ++tau)
#pragma unroll
    for (int kk = 0; kk < 4; ++kk)
      wa[tau][kk] = Wf8s[((8 * w + tau) * 4 + kk) * 64 + L];

  // lane's two output columns: tiles 8w+2q, 8w+2q+1 at col l16
  const int n0 = 128 * w + 32 * q + l16;
  const int n1 = n0 + 16;

  float A = 0.f;

  // ---- t = 0: per-wave normalized store + exponent publish (same as steady state) ----
  {
    const int id0 = ids[bT];
    float u0 = gamma[n0] * bf2f(Ptab[(long)id0 * HH + n0]) / cmax[n0];
    float u1 = gamma[n1] * bf2f(Ptab[(long)id0 * HH + n1]) / cmax[n1];
    float m = wave_max_dpp(fmaxf(u0, u1));
    int ebits = (__builtin_bit_cast(int, m) >> 23) & 0xFF;
    float nf = __builtin_bit_cast(float, (254 - ebits) << 23);  // 2^-(ebits-127)
    float x0 = u0 * nf, x1 = u1 * nf;
    unsigned pk;
    asm("v_cvt_pk_fp8_f32 %0, %1, %2" : "=v"(pk) : "v"(x0), "v"(x1));
    xbuf[n0] = (unsigned char)(pk & 0xff);
    xbuf[n1] = (unsigned char)((pk >> 8) & 0xff);
    if (L == 0) eldsb[w] = (unsigned char)ebits;
    __syncthreads();  // also publishes ids_l
  }

  unsigned short pv0c = Ptab[(long)ids_l[1] * HH + n0];
  unsigned short pv1c = Ptab[(long)ids_l[1] * HH + n1];

  for (int t = 1; t < TL; ++t) {
    const int idn = ids_l[(t + 1 < TL) ? (t + 1) : t];
    const unsigned short pv0n = Ptab[(long)idn * HH + n0];  // prefetch, rides over barrier
    const unsigned short pv1n = Ptab[(long)idn * HH + n1];

    const int pr = (t - 1) & 1, pw = t & 1;
    const unsigned char* xb = xbuf + pr * 512;

    // per-wave exponents (one b32) -> uniform per-kk scale words
    const unsigned edw = *(const unsigned*)(eldsb + pr * 4);
    const int ub0 = edw & 0xff, ub1 = (edw >> 8) & 0xff;
    const int ub2 = (edw >> 16) & 0xff, ub3 = edw >> 24;
    const int mu = max(max(ub0, ub1), max(ub2, ub3));
    A += (float)(mu - 127) * 0.69314718056f;
    const unsigned sa0 = (unsigned)max(ub0 - mu + 127, 0) * 0x01010101u;
    const unsigned sa1 = (unsigned)max(ub1 - mu + 127, 0) * 0x01010101u;
    const unsigned sa2 = (unsigned)max(ub2 - mu + 127, 0) * 0x01010101u;
    const unsigned sa3 = (unsigned)max(ub3 - mu + 127, 0) * 0x01010101u;

    const intx8 af0 = *(const intx8*)(xb + 0 * 128 + q * 32);
    const intx8 af1 = *(const intx8*)(xb + 1 * 128 + q * 32);
    const intx8 af2 = *(const intx8*)(xb + 2 * 128 + q * 32);
    const intx8 af3 = *(const intx8*)(xb + 3 * 128 + q * 32);

    floatx4 acc[8];
#pragma unroll
    for (int tau = 0; tau < 8; ++tau) acc[tau] = (floatx4){0.f, 0.f, 0.f, 0.f};

    // kk-outer, tau-inner: 8 independent insts between dependent pairs
#pragma unroll
    for (int tau = 0; tau < 8; ++tau)
      acc[tau] = __builtin_amdgcn_mfma_scale_f32_16x16x128_f8f6f4(
          af0, wa[tau][0], acc[tau], 0, 0, 0, (int)sa0, 0, 0x7F7F7F7F);
#pragma unroll
    for (int tau = 0; tau < 8; ++tau)
      acc[tau] = __builtin_amdgcn_mfma_scale_f32_16x16x128_f8f6f4(
          af1, wa[tau][1], acc[tau], 0, 0, 0, (int)sa1, 0, 0x7F7F7F7F);
#pragma unroll
    for (int tau = 0; tau < 8; ++tau)
      acc[tau] = __builtin_amdgcn_mfma_scale_f32_16x16x128_f8f6f4(
          af2, wa[tau][2], acc[tau], 0, 0, 0, (int)sa2, 0, 0x7F7F7F7F);
#pragma unroll
    for (int tau = 0; tau < 8; ++tau)
      acc[tau] = __builtin_amdgcn_mfma_scale_f32_16x16x128_f8f6f4(
          af3, wa[tau][3], acc[tau], 0, 0, 0, (int)sa3, 0, 0x7F7F7F7F);

    const float z0 = (q < 2) ? (q == 0 ? acc[0][0] : acc[2][0])
                             : (q == 2 ? acc[4][0] : acc[6][0]);
    const float z1 = (q < 2) ? (q == 0 ? acc[1][0] : acc[3][0])
                             : (q == 2 ? acc[5][0] : acc[7][0]);
    const float un0 = z0 * bf2f(pv0c);
    const float un1 = z1 * bf2f(pv1c);

    if (t == TL - 1) {
      out[(long)b * HH + n0] = __logf(fmaxf(un0, 1e-37f)) + A;
      out[(long)b * HH + n1] = __logf(fmaxf(un1, 1e-37f)) + A;
    } else {
      float m = wave_max_dpp(fmaxf(un0, un1));
      int ebits = (__builtin_bit_cast(int, m) >> 23) & 0xFF;
      float nf = __builtin_bit_cast(float, (254 - ebits) << 23);
      float x0 = un0 * nf, x1 = un1 * nf;  // per-wave normalized, max in [1,2)
      unsigned pk;
      asm("v_cvt_pk_fp8_f32 %0, %1, %2" : "=v"(pk) : "v"(x0), "v"(x1));
      xbuf[pw * 512 + n0] = (unsigned char)(pk & 0xff);
      xbuf[pw * 512 + n1] = (unsigned char)((pk >> 8) & 0xff);
      if (L == 0) eldsb[pw * 4 + w] = (unsigned char)ebits;
      asm volatile("s_waitcnt lgkmcnt(0)" ::: "memory");  // LDS-only drain (vmcnt rides)
      __builtin_amdgcn_s_barrier();
      __builtin_amdgcn_sched_barrier(0);
    }
    pv0c = pv0n;
    pv1c = pv1n;
  }
}

extern "C" void kernel_launch(void* const* d_in, const int* in_sizes, int n_in,
                              void* d_out, int out_size, void* d_ws, size_t ws_size,
                              hipStream_t stream) {
  const float* alpha_exp = (const float*)d_in[0];
  const float* beta = (const float*)d_in[1];
  const float* gamma = (const float*)d_in[2];
  const int* ids = (const int*)d_in[3];
  float* out = (float*)d_out;

  char* ws = (char*)d_ws;
  float* cmax = (float*)(ws + 0);                         // [0, 2048)
  intx8* Wf8s = (intx8*)(ws + 4096);                      // [4096, 266240) 256 KB
  unsigned short* Ptab = (unsigned short*)(ws + 528384);  // ~51.5 MB (ws proven >= 104 MB)

  // idempotent, host-side (not a stream op; graph-capture safe), every call:
  (void)hipFuncSetAttribute((const void*)hmm_main,
                            hipFuncAttributeMaxDynamicSharedMemorySize, DYN_LDS);

  colmaxK<<<8, 256, 0, stream>>>(alpha_exp, cmax);
  buildWf8sK<<<32, 256, 0, stream>>>(alpha_exp, cmax, Wf8s);
  dim3 gT((VV + 31) / 32, HH / 32), bTd(32, 8);
  buildPtab<<<gT, bTd, 0, stream>>>(beta, cmax, Ptab);

  hmm_main<<<64, NT, DYN_LDS, stream>>>(Wf8s, Ptab, gamma, cmax, ids, out);
}

// Round 10
// 617.636 us; speedup vs baseline: 20.1960x; 1.0029x over previous
//
#include <hip/hip_runtime.h>
#include <hip/hip_bf16.h>

#define HH 512
#define VV 50257
#define TL 512
#define NT 256          // 4 waves, 1 wave/SIMD; W fully register-resident per wave
#define DYN_LDS 98304   // ~3.1 KB used; big request keeps the CU exclusive

typedef __attribute__((ext_vector_type(4))) float floatx4;
typedef __attribute__((ext_vector_type(8))) int intx8;

__device__ __forceinline__ unsigned short f2bf(float f) {
  union { float f; unsigned int u; } v; v.f = f;
  unsigned int r = (v.u + 0x7fffu + ((v.u >> 16) & 1u)) >> 16;
  return (unsigned short)r;
}
__device__ __forceinline__ float bf2f(unsigned short h) {
  union { unsigned int u; float f; } v; v.u = ((unsigned int)h) << 16;
  return v.f;
}

// wave64 max via DPP (all VALU, no LDS); lane63 ends with global max, readlane bcasts.
__device__ __forceinline__ float wave_max_dpp(float x) {
  int xi = __builtin_bit_cast(int, x);
#define DPPSTEP(ctrl)                                                              \
  {                                                                                \
    int yi = __builtin_amdgcn_update_dpp(xi, xi, (ctrl), 0xf, 0xf, false);         \
    float a = __builtin_bit_cast(float, xi), b = __builtin_bit_cast(float, yi);    \
    xi = __builtin_bit_cast(int, fmaxf(a, b));                                     \
  }
  DPPSTEP(0xB1)   // quad_perm [1,0,3,2]
  DPPSTEP(0x4E)   // quad_perm [2,3,0,1]
  DPPSTEP(0x141)  // row_half_mirror
  DPPSTEP(0x140)  // row_mirror
  DPPSTEP(0x142)  // row_bcast15
  DPPSTEP(0x143)  // row_bcast31 -> lane 63 = global max
#undef DPPSTEP
  return __builtin_bit_cast(float, __builtin_amdgcn_readlane(xi, 63));
}

// ---- P1: column max of alpha_exp (+eps) ----
__global__ void colmaxK(const float* __restrict__ A, float* __restrict__ cmax) {
  __shared__ float red[4][64];
  int x = threadIdx.x & 63;
  int y = threadIdx.x >> 6;
  int c = blockIdx.x * 64 + x;
  float m = -INFINITY;
  for (int j = y; j < HH; j += 4) m = fmaxf(m, A[j * HH + c]);
  red[y][x] = m;
  __syncthreads();
  if (y == 0)
    cmax[c] = fmaxf(fmaxf(red[0][x], red[1][x]), fmaxf(red[2][x], red[3][x])) + 1e-12f;
}

// ---- P2: fp8 Wn pre-swizzled for mfma_scale 16x16x128 (B-fragment order) ----
__global__ void buildWf8sK(const float* __restrict__ A, const float* __restrict__ cmax,
                           intx8* __restrict__ Wf8s) {
  int gid = blockIdx.x * 256 + threadIdx.x;  // 0..8191
  int L = gid & 63, r = gid >> 6;            // r = T*4 + kk
  int kk = r & 3, T = r >> 2;
  int n = T * 16 + (L & 15);
  int kbase = kk * 128 + (L >> 4) * 32;
  float inv = 1.0f / cmax[n];
  intx8 o;
#pragma unroll
  for (int d = 0; d < 8; ++d) {
    float v0 = (A[(kbase + 4 * d + 0) * HH + n] + 1e-12f) * inv;
    float v1 = (A[(kbase + 4 * d + 1) * HH + n] + 1e-12f) * inv;
    float v2 = (A[(kbase + 4 * d + 2) * HH + n] + 1e-12f) * inv;
    float v3 = (A[(kbase + 4 * d + 3) * HH + n] + 1e-12f) * inv;
    unsigned pk;
    asm("v_cvt_pk_fp8_f32 %0, %1, %2" : "=v"(pk) : "v"(v0), "v"(v1));
    asm("v_cvt_pk_fp8_f32 %0, %1, %2 op_sel:[0,0,1]" : "+v"(pk) : "v"(v2), "v"(v3));
    o[d] = (int)pk;
  }
  Wf8s[gid] = o;
}

// ---- P3: Ptab[v][n] = bf16( exp(beta[n][v]) * cmax[n] ) ----
// 64x64 tile, block (64,4): reads 256B/wave contiguous in v, writes 128B/wave
// contiguous in h (the old (32,8) version wrote scattered 64B half-lines).
__global__ void buildPtab(const float* __restrict__ beta, const float* __restrict__ cmax,
                          unsigned short* __restrict__ Ptab) {
  __shared__ float tile[64][65];
  const int v0 = blockIdx.x * 64, h0 = blockIdx.y * 64;
  const int tx = threadIdx.x, ty = threadIdx.y;  // (64,4)
  const int v = v0 + tx;
#pragma unroll
  for (int k = 0; k < 16; ++k) {
    int hp = ty + 4 * k;  // 0..63
    if (v < VV) tile[hp][tx] = beta[(long)(h0 + hp) * VV + v];
  }
  __syncthreads();
  const float cm = cmax[h0 + tx];
#pragma unroll
  for (int k = 0; k < 16; ++k) {
    int vp = ty + 4 * k;  // 0..63
    int vv = v0 + vp;
    if (vv < VV) Ptab[(long)vv * HH + h0 + tx] = f2bf(__expf(tile[tx][vp]) * cm);
  }
}

// ---- Main: 64 blocks, 4 waves (1/SIMD). W register-resident fp8 MX order (256 regs).
// Round-8 structure verbatim (known good, 421us): per-step = head(edw+sa ~180cy) +
// 32 MFMA issue (1107cy) + last-MFMA latency (~400cy) + tail(DPP+pack+barrier ~290cy).
// Per-wave exponent norm carried in MX A-scales; 1 barrier/step; depth-2 buffers.
__global__ __launch_bounds__(NT, 1) __attribute__((amdgpu_waves_per_eu(1, 1)))
void hmm_main(const intx8* __restrict__ Wf8s,
              const unsigned short* __restrict__ Ptab,
              const float* __restrict__ gamma,
              const float* __restrict__ cmax,
              const int* __restrict__ ids,
              float* __restrict__ out) {
  extern __shared__ char dls[];
  unsigned char* xbuf = (unsigned char*)dls;            // [2][512] fp8 (per-wave norm)
  unsigned char* eldsb = (unsigned char*)(dls + 1024);  // [2][4] exponent bytes
  int* ids_l = (int*)(dls + 1040);                      // [512]

  const int b = blockIdx.x, tid = threadIdx.x;
  const int w = tid >> 6, L = tid & 63;
  const int q = L >> 4, l16 = L & 15;
  const long bT = (long)b * TL;

  ids_l[tid] = ids[bT + tid];
  ids_l[tid + 256] = ids[bT + tid + 256];

  // register-resident W: wave w owns n-tiles 8w..8w+7, all 4 kk (256 regs)
  intx8 wa[8][4];
#pragma unroll
  for (int tau = 0; tau < 8; ++tau)
#pragma unroll
    for (int kk = 0; kk < 4; ++kk)
      wa[tau][kk] = Wf8s[((8 * w + tau) * 4 + kk) * 64 + L];

  // lane's two output columns: tiles 8w+2q, 8w+2q+1 at col l16
  const int n0 = 128 * w + 32 * q + l16;
  const int n1 = n0 + 16;

  float A = 0.f;

  // ---- t = 0: per-wave normalized store + exponent publish (same as steady state) ----
  {
    const int id0 = ids[bT];
    float u0 = gamma[n0] * bf2f(Ptab[(long)id0 * HH + n0]) / cmax[n0];
    float u1 = gamma[n1] * bf2f(Ptab[(long)id0 * HH + n1]) / cmax[n1];
    float m = wave_max_dpp(fmaxf(u0, u1));
    int ebits = (__builtin_bit_cast(int, m) >> 23) & 0xFF;
    float nf = __builtin_bit_cast(float, (254 - ebits) << 23);  // 2^-(ebits-127)
    float x0 = u0 * nf, x1 = u1 * nf;
    unsigned pk;
    asm("v_cvt_pk_fp8_f32 %0, %1, %2" : "=v"(pk) : "v"(x0), "v"(x1));
    xbuf[n0] = (unsigned char)(pk & 0xff);
    xbuf[n1] = (unsigned char)((pk >> 8) & 0xff);
    if (L == 0) eldsb[w] = (unsigned char)ebits;
    __syncthreads();  // also publishes ids_l
  }

  unsigned short pv0c = Ptab[(long)ids_l[1] * HH + n0];
  unsigned short pv1c = Ptab[(long)ids_l[1] * HH + n1];

  for (int t = 1; t < TL; ++t) {
    const int idn = ids_l[(t + 1 < TL) ? (t + 1) : t];
    const unsigned short pv0n = Ptab[(long)idn * HH + n0];  // prefetch, rides over barrier
    const unsigned short pv1n = Ptab[(long)idn * HH + n1];

    const int pr = (t - 1) & 1, pw = t & 1;
    const unsigned char* xb = xbuf + pr * 512;

    // per-wave exponents (one b32) -> uniform per-kk scale words
    const unsigned edw = *(const unsigned*)(eldsb + pr * 4);
    const int ub0 = edw & 0xff, ub1 = (edw >> 8) & 0xff;
    const int ub2 = (edw >> 16) & 0xff, ub3 = edw >> 24;
    const int mu = max(max(ub0, ub1), max(ub2, ub3));
    A += (float)(mu - 127) * 0.69314718056f;
    const unsigned sa0 = (unsigned)max(ub0 - mu + 127, 0) * 0x01010101u;
    const unsigned sa1 = (unsigned)max(ub1 - mu + 127, 0) * 0x01010101u;
    const unsigned sa2 = (unsigned)max(ub2 - mu + 127, 0) * 0x01010101u;
    const unsigned sa3 = (unsigned)max(ub3 - mu + 127, 0) * 0x01010101u;

    const intx8 af0 = *(const intx8*)(xb + 0 * 128 + q * 32);
    const intx8 af1 = *(const intx8*)(xb + 1 * 128 + q * 32);
    const intx8 af2 = *(const intx8*)(xb + 2 * 128 + q * 32);
    const intx8 af3 = *(const intx8*)(xb + 3 * 128 + q * 32);

    floatx4 acc[8];
#pragma unroll
    for (int tau = 0; tau < 8; ++tau) acc[tau] = (floatx4){0.f, 0.f, 0.f, 0.f};

    // kk-outer, tau-inner: 8 independent insts between dependent pairs
#pragma unroll
    for (int tau = 0; tau < 8; ++tau)
      acc[tau] = __builtin_amdgcn_mfma_scale_f32_16x16x128_f8f6f4(
          af0, wa[tau][0], acc[tau], 0, 0, 0, (int)sa0, 0, 0x7F7F7F7F);
#pragma unroll
    for (int tau = 0; tau < 8; ++tau)
      acc[tau] = __builtin_amdgcn_mfma_scale_f32_16x16x128_f8f6f4(
          af1, wa[tau][1], acc[tau], 0, 0, 0, (int)sa1, 0, 0x7F7F7F7F);
#pragma unroll
    for (int tau = 0; tau < 8; ++tau)
      acc[tau] = __builtin_amdgcn_mfma_scale_f32_16x16x128_f8f6f4(
          af2, wa[tau][2], acc[tau], 0, 0, 0, (int)sa2, 0, 0x7F7F7F7F);
#pragma unroll
    for (int tau = 0; tau < 8; ++tau)
      acc[tau] = __builtin_amdgcn_mfma_scale_f32_16x16x128_f8f6f4(
          af3, wa[tau][3], acc[tau], 0, 0, 0, (int)sa3, 0, 0x7F7F7F7F);

    const float z0 = (q < 2) ? (q == 0 ? acc[0][0] : acc[2][0])
                             : (q == 2 ? acc[4][0] : acc[6][0]);
    const float z1 = (q < 2) ? (q == 0 ? acc[1][0] : acc[3][0])
                             : (q == 2 ? acc[5][0] : acc[7][0]);
    const float un0 = z0 * bf2f(pv0c);
    const float un1 = z1 * bf2f(pv1c);

    if (t == TL - 1) {
      out[(long)b * HH + n0] = __logf(fmaxf(un0, 1e-37f)) + A;
      out[(long)b * HH + n1] = __logf(fmaxf(un1, 1e-37f)) + A;
    } else {
      float m = wave_max_dpp(fmaxf(un0, un1));
      int ebits = (__builtin_bit_cast(int, m) >> 23) & 0xFF;
      float nf = __builtin_bit_cast(float, (254 - ebits) << 23);
      float x0 = un0 * nf, x1 = un1 * nf;  // per-wave normalized, max in [1,2)
      unsigned pk;
      asm("v_cvt_pk_fp8_f32 %0, %1, %2" : "=v"(pk) : "v"(x0), "v"(x1));
      xbuf[pw * 512 + n0] = (unsigned char)(pk & 0xff);
      xbuf[pw * 512 + n1] = (unsigned char)((pk >> 8) & 0xff);
      if (L == 0) eldsb[pw * 4 + w] = (unsigned char)ebits;
      asm volatile("s_waitcnt lgkmcnt(0)" ::: "memory");  // LDS-only drain (vmcnt rides)
      __builtin_amdgcn_s_barrier();
      __builtin_amdgcn_sched_barrier(0);
    }
    pv0c = pv0n;
    pv1c = pv1n;
  }
}

extern "C" void kernel_launch(void* const* d_in, const int* in_sizes, int n_in,
                              void* d_out, int out_size, void* d_ws, size_t ws_size,
                              hipStream_t stream) {
  const float* alpha_exp = (const float*)d_in[0];
  const float* beta = (const float*)d_in[1];
  const float* gamma = (const float*)d_in[2];
  const int* ids = (const int*)d_in[3];
  float* out = (float*)d_out;

  char* ws = (char*)d_ws;
  float* cmax = (float*)(ws + 0);                         // [0, 2048)
  intx8* Wf8s = (intx8*)(ws + 4096);                      // [4096, 266240) 256 KB
  unsigned short* Ptab = (unsigned short*)(ws + 528384);  // ~51.5 MB (ws proven >= 104 MB)

  // idempotent, host-side (not a stream op; graph-capture safe), every call:
  (void)hipFuncSetAttribute((const void*)hmm_main,
                            hipFuncAttributeMaxDynamicSharedMemorySize, DYN_LDS);

  colmaxK<<<8, 256, 0, stream>>>(alpha_exp, cmax);
  buildWf8sK<<<32, 256, 0, stream>>>(alpha_exp, cmax, Wf8s);
  dim3 gT((VV + 63) / 64, HH / 64), bTd(64, 4);
  buildPtab<<<gT, bTd, 0, stream>>>(beta, cmax, Ptab);

  hmm_main<<<64, NT, DYN_LDS, stream>>>(Wf8s, Ptab, gamma, cmax, ids, out);
}